// Round 3
// baseline (159.991 us; speedup 1.0000x reference)
//
#include <hip/hip_runtime.h>
#include <hip/hip_bf16.h>

// ---------- types ----------
typedef unsigned short ushortT;
typedef __bf16 bf16x8 __attribute__((ext_vector_type(8)));
typedef float f32x4 __attribute__((ext_vector_type(4)));
typedef ushortT ush8 __attribute__((ext_vector_type(8)));
typedef ushortT ush4 __attribute__((ext_vector_type(4)));

#define MFMA16(a, b, c) __builtin_amdgcn_mfma_f32_16x16x32_bf16((a), (b), (c), 0, 0, 0)

__device__ __forceinline__ ushortT f2b(float f) {
  __hip_bfloat16 h = __float2bfloat16(f);
  return __builtin_bit_cast(ushortT, h);
}
__device__ __forceinline__ float b2f(ushortT u) {
  __hip_bfloat16 h = __builtin_bit_cast(__hip_bfloat16, u);
  return __bfloat162float(h);
}

// async global->LDS, 16B per lane
__device__ __forceinline__ void async16(const void* g, void* l) {
  __builtin_amdgcn_global_load_lds((const __attribute__((address_space(1))) unsigned int*)g,
                                   (__attribute__((address_space(3))) unsigned int*)l, 16, 0, 0);
}

// ---------- problem dims ----------
// B=4, S=512, D=256, ROWS = B*S = 2048
#define ACT_E 524288   // 2048*256 elements
#define WD_E  65536    // 256*256

// ---------- ws layout (bytes) ----------
// transient zone [0, ~27.4MB): act16/actT16/w16t/proj16/P16/vc/ac/pvv/pva
// PART (33.5MB) overlaps the transient zone (all dead when bilinear runs).
#define OFF_ACT16   0u          // 3 * ACT_E * 2 = 3145728
#define OFF_ACTT16  3145728u    // 3 * ACT_E * 2
#define OFF_W16T    6291456u    // 9 * WD_E * 2 = 1179648
#define OFF_PROJ16  7471104u    // 5 * ACT_E * 2 = 5242880
#define OFF_P16     12713984u   // 4 * 1048576 * 2 = 8388608
#define OFF_VC16    21102592u   // ACT_E*2
#define OFF_AC16    22151168u
#define OFF_PVV32   23199744u   // ACT_E*4
#define OFF_PVA32   25296896u   // ends 27394048
#define OFF_PART    0u          // 16 * 2048*256*4 = 33554432 (overlaps transients)
#define OFF_BIL16   33554432u   // 16777216*2 = 33554432, ends 67108864
#define OFF_CFV16   67108864u   // ACT_E*2
#define OFF_CFA16   68157440u   // ends 69206016

// =====================================================================
// 1) convert img/audio/common fp32 -> bf16 (same layout)
__global__ void k_cvt_acts(const float* __restrict__ img, const float* __restrict__ aud,
                           const float* __restrict__ com, ushortT* __restrict__ dst) {
  int i4 = blockIdx.x * 256 + threadIdx.x;
#pragma unroll
  for (int q = 0; q < 4; q++) {
    int idx4 = i4 + q * 98304;
    int flat = idx4 * 4;
    const float* src;
    int off;
    if (flat < 524288)        { src = img; off = flat; }
    else if (flat < 1048576)  { src = aud; off = flat - 524288; }
    else                      { src = com; off = flat - 1048576; }
    float4 v = *(const float4*)(src + off);
    ush4 u = { f2b(v.x), f2b(v.y), f2b(v.z), f2b(v.w) };
    *(ush4*)(dst + idx4 * 4) = u;
  }
}

// 2) convert bil_w fp32 -> bf16
__global__ void k_cvt_bil(const float* __restrict__ bil, ushortT* __restrict__ dst) {
  int i4 = blockIdx.x * 256 + threadIdx.x;
#pragma unroll
  for (int q = 0; q < 8; q++) {
    int idx4 = i4 + q * 524288;
    float4 v = *(const float4*)(bil + idx4 * 4);
    ush4 u = { f2b(v.x), f2b(v.y), f2b(v.z), f2b(v.w) };
    *(ush4*)(dst + idx4 * 4) = u;
  }
}

// 3) transpose+convert
__global__ void k_transpose(const float* __restrict__ img, const float* __restrict__ aud,
                            const float* __restrict__ com,
                            const float* w0, const float* w1, const float* w2,
                            const float* w3, const float* w4, const float* w5,
                            const float* w6, const float* w7, const float* w8,
                            ushortT* __restrict__ actT, ushortT* __restrict__ wT) {
  __shared__ ushortT tl[64][72];
  int tid = threadIdx.x;
  int bx = blockIdx.x;
  const float* src;
  ushortT* dst;
  int R, C, r0, c0;
  if (bx < 384) {
    int inst = bx >> 5, tile = bx & 31;
    int act = inst >> 2, bb = inst & 3;
    src = (act == 0 ? img : (act == 1 ? aud : com)) + bb * 131072;
    dst = actT + act * 524288 + bb * 131072;
    R = 512; C = 256;
    r0 = (tile >> 2) * 64; c0 = (tile & 3) * 64;
  } else {
    int bw = bx - 384;
    int w = bw >> 4, tile = bw & 15;
    const float* s;
    switch (w) {
      case 0: s = w0; break; case 1: s = w1; break; case 2: s = w2; break;
      case 3: s = w3; break; case 4: s = w4; break; case 5: s = w5; break;
      case 6: s = w6; break; case 7: s = w7; break; default: s = w8; break;
    }
    src = s;
    dst = wT + w * 65536;
    R = 256; C = 256;
    r0 = (tile >> 2) * 64; c0 = (tile & 3) * 64;
  }
#pragma unroll
  for (int q = 0; q < 4; q++) {
    int rr = q * 16 + (tid >> 4);
    int cs = (tid & 15) * 4;
    float4 v = *(const float4*)(src + (r0 + rr) * C + c0 + cs);
    tl[rr][cs + 0] = f2b(v.x);
    tl[rr][cs + 1] = f2b(v.y);
    tl[rr][cs + 2] = f2b(v.z);
    tl[rr][cs + 3] = f2b(v.w);
  }
  __syncthreads();
#pragma unroll
  for (int q = 0; q < 4; q++) {
    int cc = q * 16 + (tid >> 4);
    int rs = (tid & 15) * 4;
    ush4 u = { tl[rs + 0][cc], tl[rs + 1][cc], tl[rs + 2][cc], tl[rs + 3][cc] };
    *(ush4*)(dst + (c0 + cc) * R + r0 + rs) = u;
  }
}

// =====================================================================
// 4) five input linears
__global__ __launch_bounds__(512) void k_linear5(
    const ushortT* __restrict__ act16, const ushortT* __restrict__ wT,
    const float* __restrict__ b0, const float* __restrict__ b1,
    const float* __restrict__ b2, const float* __restrict__ b3,
    const float* __restrict__ b4, ushortT* __restrict__ proj16) {
  __shared__ ushortT Al[4][32][8];
  __shared__ ushortT Bl[4][256][8];
  const int tid = threadIdx.x, l = tid & 63, w = tid >> 6;
  const int bx = blockIdx.x;
  const int op = bx >> 6, sblk = bx & 63;
  const int s0 = sblk * 32;
  const int xsel = (op == 4) ? 2 : (op & 1);
  const ushortT* X = act16 + xsel * ACT_E;
  const ushortT* W = wT + op * WD_E;
  const float* bias = op == 0 ? b0 : op == 1 ? b1 : op == 2 ? b2 : op == 3 ? b3 : b4;
  ushortT* out = proj16 + op * ACT_E;

  f32x4 acc[2][2] = {};
  ush8 ra, rb[2];
  int a_row = tid >> 2, a_seg = tid & 3;

  auto sload = [&](int k0) {
    if (tid < 128) ra = *(const ush8*)(X + (s0 + a_row) * 256 + k0 + a_seg * 8);
#pragma unroll
    for (int q = 0; q < 2; q++) {
      int slot = tid + q * 512;
      rb[q] = *(const ush8*)(W + (slot >> 2) * 256 + k0 + (slot & 3) * 8);
    }
  };
  auto swrite = [&]() {
    if (tid < 128) *(ush8*)(&Al[a_seg][a_row][0]) = ra;
#pragma unroll
    for (int q = 0; q < 2; q++) {
      int slot = tid + q * 512;
      *(ush8*)(&Bl[slot & 3][slot >> 2][0]) = rb[q];
    }
  };

  sload(0); swrite(); __syncthreads();
  for (int s = 0; s < 8; s++) {
    if (s < 7) sload((s + 1) * 32);
    int ks = l >> 4;
    bf16x8 a[2], bb[2];
#pragma unroll
    for (int m = 0; m < 2; m++) a[m] = *(const bf16x8*)(&Al[ks][m * 16 + (l & 15)][0]);
#pragma unroll
    for (int n = 0; n < 2; n++) bb[n] = *(const bf16x8*)(&Bl[ks][w * 32 + n * 16 + (l & 15)][0]);
#pragma unroll
    for (int m = 0; m < 2; m++)
#pragma unroll
      for (int n = 0; n < 2; n++) acc[m][n] = MFMA16(a[m], bb[n], acc[m][n]);
    if (s == 7) break;
    __syncthreads();
    swrite();
    __syncthreads();
  }
#pragma unroll
  for (int m = 0; m < 2; m++)
#pragma unroll
    for (int n = 0; n < 2; n++)
#pragma unroll
      for (int r = 0; r < 4; r++) {
        int row = s0 + m * 16 + (l >> 4) * 4 + r;
        int col = w * 32 + n * 16 + (l & 15);
        out[row * 256 + col] = f2b(acc[m][n][r] + bias[col]);
      }
}

// =====================================================================
// 5) attention: P = softmax(Q K^T) * (1/16)
__global__ __launch_bounds__(512) void k_attn(const ushortT* __restrict__ proj16,
                                              ushortT* __restrict__ P16) {
  __shared__ ushortT Ql[8][4][32][8];
  __shared__ ushortT Kl[4][512][8];
  __shared__ float red[32][8];
  const int tid = threadIdx.x, l = tid & 63, w = tid >> 6;
  const int bx = blockIdx.x;
  const int p = bx >> 6, b = (bx >> 4) & 3, sblk = bx & 15;
  const int s0 = sblk * 32;
  const int qsel = (p < 2) ? 0 : 1;
  const int ksel = (p == 0) ? 2 : (p == 2) ? 3 : 4;
  const ushortT* Q = proj16 + qsel * ACT_E + b * 131072;
  const ushortT* K = proj16 + ksel * ACT_E + b * 131072;
  ushortT* P = P16 + p * 1048576 + b * 262144;

#pragma unroll
  for (int q = 0; q < 2; q++) {
    int slot = tid + q * 512;
    int row = slot >> 5, seg = slot & 31;
    ush8 v = *(const ush8*)(Q + (s0 + row) * 256 + seg * 8);
    *(ush8*)(&Ql[seg >> 2][seg & 3][row][0]) = v;
  }

  f32x4 acc[2][4] = {};
  ush8 rk[4];
  auto kload = [&](int d0) {
#pragma unroll
    for (int q = 0; q < 4; q++) {
      int slot = tid + q * 512;
      rk[q] = *(const ush8*)(K + (slot >> 2) * 256 + d0 + (slot & 3) * 8);
    }
  };
  auto kwrite = [&]() {
#pragma unroll
    for (int q = 0; q < 4; q++) {
      int slot = tid + q * 512;
      *(ush8*)(&Kl[slot & 3][slot >> 2][0]) = rk[q];
    }
  };

  kload(0); kwrite(); __syncthreads();
  for (int s = 0; s < 8; s++) {
    if (s < 7) kload((s + 1) * 32);
    int ks = l >> 4;
    bf16x8 a[2], bb[4];
#pragma unroll
    for (int m = 0; m < 2; m++) a[m] = *(const bf16x8*)(&Ql[s][ks][m * 16 + (l & 15)][0]);
#pragma unroll
    for (int n = 0; n < 4; n++) bb[n] = *(const bf16x8*)(&Kl[ks][w * 64 + n * 16 + (l & 15)][0]);
#pragma unroll
    for (int m = 0; m < 2; m++)
#pragma unroll
      for (int n = 0; n < 4; n++) acc[m][n] = MFMA16(a[m], bb[n], acc[m][n]);
    if (s == 7) break;
    __syncthreads();
    kwrite();
    __syncthreads();
  }

  float gmax[2][4];
#pragma unroll
  for (int m = 0; m < 2; m++)
#pragma unroll
    for (int r = 0; r < 4; r++) {
      float v = fmaxf(fmaxf(acc[m][0][r], acc[m][1][r]), fmaxf(acc[m][2][r], acc[m][3][r]));
#pragma unroll
      for (int off = 1; off < 16; off <<= 1) v = fmaxf(v, __shfl_xor(v, off, 16));
      if ((l & 15) == 0) red[m * 16 + (l >> 4) * 4 + r][w] = v;
    }
  __syncthreads();
#pragma unroll
  for (int m = 0; m < 2; m++)
#pragma unroll
    for (int r = 0; r < 4; r++) {
      int sr = m * 16 + (l >> 4) * 4 + r;
      float g = red[sr][0];
#pragma unroll
      for (int ww = 1; ww < 8; ww++) g = fmaxf(g, red[sr][ww]);
      gmax[m][r] = g;
    }
  __syncthreads();
#pragma unroll
  for (int m = 0; m < 2; m++)
#pragma unroll
    for (int r = 0; r < 4; r++) {
      float ssum = 0.f;
#pragma unroll
      for (int n = 0; n < 4; n++) {
        float e = __expf(acc[m][n][r] - gmax[m][r]);
        acc[m][n][r] = e;
        ssum += e;
      }
#pragma unroll
      for (int off = 1; off < 16; off <<= 1) ssum += __shfl_xor(ssum, off, 16);
      if ((l & 15) == 0) red[m * 16 + (l >> 4) * 4 + r][w] = ssum;
    }
  __syncthreads();
#pragma unroll
  for (int m = 0; m < 2; m++)
#pragma unroll
    for (int r = 0; r < 4; r++) {
      int sr = m * 16 + (l >> 4) * 4 + r;
      float tot = 0.f;
#pragma unroll
      for (int ww = 0; ww < 8; ww++) tot += red[sr][ww];
      float sc = 0.0625f / tot;
#pragma unroll
      for (int n = 0; n < 4; n++)
        P[(s0 + sr) * 512 + w * 64 + n * 16 + (l & 15)] = f2b(acc[m][n][r] * sc);
    }
}

// =====================================================================
// 6) PV products
__global__ __launch_bounds__(512) void k_pv(const ushortT* __restrict__ P16,
                                            const ushortT* __restrict__ actT,
                                            float* __restrict__ pvv, float* __restrict__ pva,
                                            ushortT* __restrict__ vc16, ushortT* __restrict__ ac16) {
  __shared__ ushortT Al[4][32][8];
  __shared__ ushortT Bl[4][256][8];
  const int tid = threadIdx.x, l = tid & 63, w = tid >> 6;
  const int bx = blockIdx.x;
  const int p = bx >> 6, b = (bx >> 4) & 3, sblk = bx & 15;
  const int s0 = sblk * 32;
  const ushortT* A = P16 + p * 1048576 + b * 262144;
  const int vsel = (p == 0) ? 0 : (p == 2) ? 1 : 2;
  const ushortT* VT = actT + vsel * ACT_E + b * 131072;

  f32x4 acc[2][2] = {};
  ush8 ra, rb[2];
  int a_row = tid >> 2, a_seg = tid & 3;
  auto sload = [&](int t0) {
    if (tid < 128) ra = *(const ush8*)(A + (s0 + a_row) * 512 + t0 + a_seg * 8);
#pragma unroll
    for (int q = 0; q < 2; q++) {
      int slot = tid + q * 512;
      rb[q] = *(const ush8*)(VT + (slot >> 2) * 512 + t0 + (slot & 3) * 8);
    }
  };
  auto swrite = [&]() {
    if (tid < 128) *(ush8*)(&Al[a_seg][a_row][0]) = ra;
#pragma unroll
    for (int q = 0; q < 2; q++) {
      int slot = tid + q * 512;
      *(ush8*)(&Bl[slot & 3][slot >> 2][0]) = rb[q];
    }
  };

  sload(0); swrite(); __syncthreads();
  for (int s = 0; s < 16; s++) {
    if (s < 15) sload((s + 1) * 32);
    int ks = l >> 4;
    bf16x8 a[2], bb[2];
#pragma unroll
    for (int m = 0; m < 2; m++) a[m] = *(const bf16x8*)(&Al[ks][m * 16 + (l & 15)][0]);
#pragma unroll
    for (int n = 0; n < 2; n++) bb[n] = *(const bf16x8*)(&Bl[ks][w * 32 + n * 16 + (l & 15)][0]);
#pragma unroll
    for (int m = 0; m < 2; m++)
#pragma unroll
      for (int n = 0; n < 2; n++) acc[m][n] = MFMA16(a[m], bb[n], acc[m][n]);
    if (s == 15) break;
    __syncthreads();
    swrite();
    __syncthreads();
  }
#pragma unroll
  for (int m = 0; m < 2; m++)
#pragma unroll
    for (int n = 0; n < 2; n++)
#pragma unroll
      for (int r = 0; r < 4; r++) {
        int row = s0 + m * 16 + (l >> 4) * 4 + r;
        int col = w * 32 + n * 16 + (l & 15);
        int gi = (b * 512 + row) * 256 + col;
        float v = acc[m][n][r];
        if (p == 0) pvv[gi] = v;
        else if (p == 1) vc16[gi] = f2b(v);
        else if (p == 2) pva[gi] = v;
        else ac16[gi] = f2b(v);
      }
}

// =====================================================================
// 7) two linears + combine
__global__ __launch_bounds__(512) void k_lin4c(
    const ushortT* __restrict__ vc16, const ushortT* __restrict__ ac16,
    const ushortT* __restrict__ wT,
    const float* __restrict__ w5b, const float* __restrict__ w6b,
    const float* __restrict__ w7b, const float* __restrict__ w8b,
    const float* __restrict__ pvv, const float* __restrict__ pva,
    ushortT* __restrict__ cfv, ushortT* __restrict__ cfa) {
  __shared__ ushortT Al[4][32][8];
  __shared__ ushortT B1[4][256][8];
  __shared__ ushortT B2[4][256][8];
  const int tid = threadIdx.x, l = tid & 63, w = tid >> 6;
  const int bx = blockIdx.x;
  const int side = bx >> 6, sblk = bx & 63;
  const int s0 = sblk * 32;
  const ushortT* A = side ? ac16 : vc16;
  const ushortT* W1 = wT + (side ? 7 : 5) * WD_E;
  const ushortT* W2 = wT + (side ? 8 : 6) * WD_E;
  const float* bb1 = side ? w7b : w5b;
  const float* bb2 = side ? w8b : w6b;
  const float* pv = side ? pva : pvv;
  ushortT* out = side ? cfa : cfv;

  f32x4 acc1[2][2] = {}, acc2[2][2] = {};
  ush8 ra, rb1[2], rb2[2];
  int a_row = tid >> 2, a_seg = tid & 3;
  auto sload = [&](int k0) {
    if (tid < 128) ra = *(const ush8*)(A + (s0 + a_row) * 256 + k0 + a_seg * 8);
#pragma unroll
    for (int q = 0; q < 2; q++) {
      int slot = tid + q * 512;
      rb1[q] = *(const ush8*)(W1 + (slot >> 2) * 256 + k0 + (slot & 3) * 8);
      rb2[q] = *(const ush8*)(W2 + (slot >> 2) * 256 + k0 + (slot & 3) * 8);
    }
  };
  auto swrite = [&]() {
    if (tid < 128) *(ush8*)(&Al[a_seg][a_row][0]) = ra;
#pragma unroll
    for (int q = 0; q < 2; q++) {
      int slot = tid + q * 512;
      *(ush8*)(&B1[slot & 3][slot >> 2][0]) = rb1[q];
      *(ush8*)(&B2[slot & 3][slot >> 2][0]) = rb2[q];
    }
  };

  sload(0); swrite(); __syncthreads();
  for (int s = 0; s < 8; s++) {
    if (s < 7) sload((s + 1) * 32);
    int ks = l >> 4;
    bf16x8 a[2], x1[2], x2[2];
#pragma unroll
    for (int m = 0; m < 2; m++) a[m] = *(const bf16x8*)(&Al[ks][m * 16 + (l & 15)][0]);
#pragma unroll
    for (int n = 0; n < 2; n++) {
      x1[n] = *(const bf16x8*)(&B1[ks][w * 32 + n * 16 + (l & 15)][0]);
      x2[n] = *(const bf16x8*)(&B2[ks][w * 32 + n * 16 + (l & 15)][0]);
    }
#pragma unroll
    for (int m = 0; m < 2; m++)
#pragma unroll
      for (int n = 0; n < 2; n++) {
        acc1[m][n] = MFMA16(a[m], x1[n], acc1[m][n]);
        acc2[m][n] = MFMA16(a[m], x2[n], acc2[m][n]);
      }
    if (s == 7) break;
    __syncthreads();
    swrite();
    __syncthreads();
  }
#pragma unroll
  for (int m = 0; m < 2; m++)
#pragma unroll
    for (int n = 0; n < 2; n++)
#pragma unroll
      for (int r = 0; r < 4; r++) {
        int row = s0 + m * 16 + (l >> 4) * 4 + r;
        int col = w * 32 + n * 16 + (l & 15);
        int gi = row * 256 + col;
        float u1 = acc1[m][n][r] + bb1[col];
        float u2 = acc2[m][n][r] + bb2[col];
        out[gi] = f2b((1.f + u1) * pv[gi] + u2);
      }
}

// =====================================================================
// 8) bilinear v3: deep GEMM with i-fold, 2 blocks/CU.
// m[r,ko] = sum_i cfv[r,i] * ( sum_j cfa[r,j] * W[ko, i*256+j] )
// grid 512 = ic(16) x mb(16) x nb(2).  Block tile 128 rows x 128 ko,
// 256 threads (2x2 waves of 64x64). 128 K-steps (16 i x 8 j-steps, BK=32).
// 3-buffer pipeline, counted vmcnt(4), one barrier/step, global_load_lds
// staging with XOR-swizzled addressing (conflict-free b128 fragment reads).
__global__ __launch_bounds__(256, 2) void k_bilinear3(
    const ushortT* __restrict__ cfa, const ushortT* __restrict__ cfv,
    const ushortT* __restrict__ W, float* __restrict__ part) {
  // LDS arena: A 3x8192 @0, B 3x8192 @24576, cfv f32 [128][16] @49152
  __shared__ char arena[57344];
  const int tid = threadIdx.x, l = tid & 63, w = tid >> 6;
  const int bx = blockIdx.x;
  const int ic = bx >> 5;           // 0..15
  const int mb = (bx >> 1) & 15;    // 0..15
  const int nb = bx & 1;            // 0..1
  const int r0 = mb * 128;
  const int ko0 = nb * 128;
  const int wr = w >> 1, wc = w & 1;   // 2x2 waves; wave tile 64x64

  // ---- cfv slice -> LDS fp32 [128][16]
  float* cfvl = (float*)(arena + 49152);
  {
    int row = tid >> 1, seg = tid & 1;
    ush8 v = *(const ush8*)(cfv + (r0 + row) * 256 + ic * 16 + seg * 8);
    float* d = cfvl + row * 16 + seg * 8;
#pragma unroll
    for (int q = 0; q < 8; q++) d[q] = b2f(v[q]);
  }
  __syncthreads();

  // ---- staging geometry: phys slot -> logical (row,seg) via XOR involution
  // A and B tiles are both [128 rows][32 cols] bf16 = 8192 B, 64 B/row.
  int aP0 = tid * 16, aP1 = (tid + 256) * 16;
  int aL0 = aP0 ^ (((aP0 >> 7) & 7) << 4);
  int aL1 = aP1 ^ (((aP1 >> 7) & 7) << 4);
  const ushortT* gA0 = cfa + (r0 + (aL0 >> 6)) * 256 + ((aL0 >> 4) & 3) * 8;
  const ushortT* gA1 = cfa + (r0 + (aL1 >> 6)) * 256 + ((aL1 >> 4) & 3) * 8;
  const ushortT* gB0 = W + (ko0 + (aL0 >> 6)) * 65536 + ic * 4096 + ((aL0 >> 4) & 3) * 8;
  const ushortT* gB1 = W + (ko0 + (aL1 >> 6)) * 65536 + ic * 4096 + ((aL1 >> 4) & 3) * 8;

  // fragment read offsets (swizzled byte offsets within a tile)
  int aoff[4], boff[4];
#pragma unroll
  for (int m = 0; m < 4; m++) {
    int row = wr * 64 + m * 16 + (l & 15);
    int byte = row * 64 + (l >> 4) * 16;
    aoff[m] = byte ^ (((byte >> 7) & 7) << 4);
  }
#pragma unroll
  for (int n = 0; n < 4; n++) {
    int row = wc * 64 + n * 16 + (l & 15);
    int byte = row * 64 + (l >> 4) * 16;
    boff[n] = byte ^ (((byte >> 7) & 7) << 4);
  }

  f32x4 macc[4][4] = {};
  f32x4 acci[4][4] = {};

  // prologue: stage t=0 -> buf0, t=1 -> buf1 (4 loads each)
  {
    char* Ab = arena;  char* Bb = arena + 24576;
    async16(gA0 + 0, Ab + aP0);  async16(gA1 + 0, Ab + aP1);
    async16(gB0 + 0, Bb + aP0);  async16(gB1 + 0, Bb + aP1);
    Ab += 8192; Bb += 8192;
    async16(gA0 + 32, Ab + aP0); async16(gA1 + 32, Ab + aP1);
    async16(gB0 + 32, Bb + aP0); async16(gB1 + 32, Bb + aP1);
  }

  int bi = 0, si = 2;
  for (int t = 0; t < 128; t++) {
    if (t < 126) asm volatile("s_waitcnt vmcnt(4)" ::: "memory");
    else         asm volatile("s_waitcnt vmcnt(0)" ::: "memory");
    __builtin_amdgcn_s_barrier();

    char* Ab = arena + bi * 8192;
    char* Bb = arena + 24576 + bi * 8192;
    bf16x8 af[4], bf[4];
#pragma unroll
    for (int m = 0; m < 4; m++) af[m] = *(const bf16x8*)(Ab + aoff[m]);
#pragma unroll
    for (int n = 0; n < 4; n++) bf[n] = *(const bf16x8*)(Bb + boff[n]);
#pragma unroll
    for (int m = 0; m < 4; m++)
#pragma unroll
      for (int n = 0; n < 4; n++) acci[m][n] = MFMA16(af[m], bf[n], acci[m][n]);

    if ((t & 7) == 7) {
      int il = t >> 3;
#pragma unroll
      for (int m = 0; m < 4; m++) {
        int rbase = wr * 64 + m * 16 + ((l >> 4) << 2);
        float c0 = cfvl[(rbase + 0) * 16 + il];
        float c1 = cfvl[(rbase + 1) * 16 + il];
        float c2 = cfvl[(rbase + 2) * 16 + il];
        float c3 = cfvl[(rbase + 3) * 16 + il];
#pragma unroll
        for (int n = 0; n < 4; n++) {
          macc[m][n][0] += c0 * acci[m][n][0];
          macc[m][n][1] += c1 * acci[m][n][1];
          macc[m][n][2] += c2 * acci[m][n][2];
          macc[m][n][3] += c3 * acci[m][n][3];
          acci[m][n] = (f32x4){0.f, 0.f, 0.f, 0.f};
        }
      }
    }

    if (t < 126) {
      char* An = arena + si * 8192;
      char* Bn = arena + 24576 + si * 8192;
      int ts = t + 2;
      int js = (ts & 7) * 32;
      async16(gA0 + js, An + aP0);
      async16(gA1 + js, An + aP1);
      async16(gB0 + ts * 32, Bn + aP0);
      async16(gB1 + ts * 32, Bn + aP1);
    }
    bi = (bi == 2) ? 0 : bi + 1;
    si = (si == 2) ? 0 : si + 1;
  }

  // epilogue: store fp32 partial
  float* dst = part + ic * 524288 + r0 * 256 + ko0;
#pragma unroll
  for (int m = 0; m < 4; m++)
#pragma unroll
    for (int n = 0; n < 4; n++)
#pragma unroll
      for (int r = 0; r < 4; r++)
        dst[(wr * 64 + m * 16 + ((l >> 4) << 2) + r) * 256 + wc * 64 + n * 16 + (l & 15)] =
            macc[m][n][r];
}

// =====================================================================
// 9) final gate + partial reduction over 16 ic-chunks
__global__ void k_final2(const float* __restrict__ part, const float* __restrict__ img,
                         const float* __restrict__ aud, const float* __restrict__ t_o,
                         float* __restrict__ out0, float* __restrict__ out1) {
  int i = blockIdx.x * 256 + threadIdx.x;
  float t = t_o[0];
  float4 m = {0.f, 0.f, 0.f, 0.f};
#pragma unroll
  for (int ic = 0; ic < 16; ic++) {
    float4 p = ((const float4*)(part + ic * 524288))[i];
    m.x += p.x; m.y += p.y; m.z += p.z; m.w += p.w;
  }
  float4 a = ((const float4*)img)[i];
  float4 u = ((const float4*)aud)[i];
  float4 o0, o1;
  {
    float j = 1.f / (1.f + __expf(-m.x)); float Z = t * j * a.x + (1.f - j) * u.x;
    o0.x = Z + a.x; o1.x = Z + u.x;
  }
  {
    float j = 1.f / (1.f + __expf(-m.y)); float Z = t * j * a.y + (1.f - j) * u.y;
    o0.y = Z + a.y; o1.y = Z + u.y;
  }
  {
    float j = 1.f / (1.f + __expf(-m.z)); float Z = t * j * a.z + (1.f - j) * u.z;
    o0.z = Z + a.z; o1.z = Z + u.z;
  }
  {
    float j = 1.f / (1.f + __expf(-m.w)); float Z = t * j * a.w + (1.f - j) * u.w;
    o0.w = Z + a.w; o1.w = Z + u.w;
  }
  ((float4*)out0)[i] = o0;
  ((float4*)out1)[i] = o1;
}

// =====================================================================
extern "C" void kernel_launch(void* const* d_in, const int* in_sizes, int n_in,
                              void* d_out, int out_size, void* d_ws, size_t ws_size,
                              hipStream_t stream) {
  const float* img   = (const float*)d_in[0];
  const float* aud   = (const float*)d_in[1];
  const float* com   = (const float*)d_in[2];
  const float* qv_w  = (const float*)d_in[3];
  const float* qv_b  = (const float*)d_in[4];
  const float* qa_w  = (const float*)d_in[5];
  const float* qa_b  = (const float*)d_in[6];
  const float* kv_w  = (const float*)d_in[7];
  const float* kv_b  = (const float*)d_in[8];
  const float* ka_w  = (const float*)d_in[9];
  const float* ka_b  = (const float*)d_in[10];
  const float* cc_w  = (const float*)d_in[11];
  const float* cc_b  = (const float*)d_in[12];
  const float* w5_w  = (const float*)d_in[13];
  const float* w5_b  = (const float*)d_in[14];
  const float* w6_w  = (const float*)d_in[15];
  const float* w6_b  = (const float*)d_in[16];
  const float* w7_w  = (const float*)d_in[17];
  const float* w7_b  = (const float*)d_in[18];
  const float* w8_w  = (const float*)d_in[19];
  const float* w8_b  = (const float*)d_in[20];
  const float* bil_w = (const float*)d_in[21];
  const float* t_o   = (const float*)d_in[22];
  float* out = (float*)d_out;

  char* ws = (char*)d_ws;
  ushortT* act16  = (ushortT*)(ws + OFF_ACT16);
  ushortT* actT16 = (ushortT*)(ws + OFF_ACTT16);
  ushortT* w16t   = (ushortT*)(ws + OFF_W16T);
  ushortT* proj16 = (ushortT*)(ws + OFF_PROJ16);
  ushortT* P16    = (ushortT*)(ws + OFF_P16);
  ushortT* vc16   = (ushortT*)(ws + OFF_VC16);
  ushortT* ac16   = (ushortT*)(ws + OFF_AC16);
  float*   pvv32  = (float*)(ws + OFF_PVV32);
  float*   pva32  = (float*)(ws + OFF_PVA32);
  float*   part   = (float*)(ws + OFF_PART);
  ushortT* bil16  = (ushortT*)(ws + OFF_BIL16);
  ushortT* cfv16  = (ushortT*)(ws + OFF_CFV16);
  ushortT* cfa16  = (ushortT*)(ws + OFF_CFA16);

  k_cvt_acts<<<384, 256, 0, stream>>>(img, aud, com, act16);
  k_cvt_bil<<<2048, 256, 0, stream>>>(bil_w, bil16);
  k_transpose<<<528, 256, 0, stream>>>(img, aud, com, qv_w, qa_w, kv_w, ka_w, cc_w,
                                       w5_w, w6_w, w7_w, w8_w, actT16, w16t);
  k_linear5<<<320, 512, 0, stream>>>(act16, w16t, qv_b, qa_b, kv_b, ka_b, cc_b, proj16);
  k_attn<<<256, 512, 0, stream>>>(proj16, P16);
  k_pv<<<256, 512, 0, stream>>>(P16, actT16, pvv32, pva32, vc16, ac16);
  k_lin4c<<<128, 512, 0, stream>>>(vc16, ac16, w16t, w5_b, w6_b, w7_b, w8_b,
                                   pvv32, pva32, cfv16, cfa16);
  k_bilinear3<<<512, 256, 0, stream>>>(cfa16, cfv16, bil16, part);
  k_final2<<<512, 256, 0, stream>>>(part, img, aud, t_o, out, out + 524288);
}

// Round 4
// 153.314 us; speedup vs baseline: 1.0436x; 1.0436x over previous
//
#include <hip/hip_runtime.h>
#include <hip/hip_bf16.h>

// ---------- types ----------
typedef unsigned short ushortT;
typedef __bf16 bf16x8 __attribute__((ext_vector_type(8)));
typedef float f32x4 __attribute__((ext_vector_type(4)));
typedef ushortT ush8 __attribute__((ext_vector_type(8)));
typedef ushortT ush4 __attribute__((ext_vector_type(4)));

#define MFMA16(a, b, c) __builtin_amdgcn_mfma_f32_16x16x32_bf16((a), (b), (c), 0, 0, 0)

__device__ __forceinline__ ushortT f2b(float f) {
  __hip_bfloat16 h = __float2bfloat16(f);
  return __builtin_bit_cast(ushortT, h);
}
__device__ __forceinline__ float b2f(ushortT u) {
  __hip_bfloat16 h = __builtin_bit_cast(__hip_bfloat16, u);
  return __bfloat162float(h);
}

// async global->LDS, 16B per lane
__device__ __forceinline__ void async16(const void* g, void* l) {
  __builtin_amdgcn_global_load_lds((const __attribute__((address_space(1))) unsigned int*)g,
                                   (__attribute__((address_space(3))) unsigned int*)l, 16, 0, 0);
}

// ---------- problem dims ----------
// B=4, S=512, D=256, ROWS = B*S = 2048
#define ACT_E 524288   // 2048*256 elements
#define WD_E  65536    // 256*256

// ---------- ws layout (bytes) ----------
#define OFF_ACT16   0u          // 3 * ACT_E * 2 = 3145728
#define OFF_ACTT16  3145728u    // 3 * ACT_E * 2
#define OFF_W16T    6291456u    // 9 * WD_E * 2 = 1179648
#define OFF_PROJ16  7471104u    // 5 * ACT_E * 2 = 5242880
#define OFF_P16     12713984u   // 4 * 1048576 * 2 = 8388608
#define OFF_VC16    21102592u   // ACT_E*2
#define OFF_AC16    22151168u
#define OFF_PVV32   23199744u   // ACT_E*4
#define OFF_PVA32   25296896u   // ends 27394048
#define OFF_PART    0u          // 16 * 2048*256*4 = 33554432 (overlaps transients)
#define OFF_BIL16   33554432u   // 16777216*2 = 33554432, ends 67108864
#define OFF_CFV16   67108864u   // ACT_E*2
#define OFF_CFA16   68157440u   // ends 69206016

// =====================================================================
// 1) convert img/audio/common fp32 -> bf16 (same layout)
__global__ void k_cvt_acts(const float* __restrict__ img, const float* __restrict__ aud,
                           const float* __restrict__ com, ushortT* __restrict__ dst) {
  int i4 = blockIdx.x * 256 + threadIdx.x;
#pragma unroll
  for (int q = 0; q < 4; q++) {
    int idx4 = i4 + q * 98304;
    int flat = idx4 * 4;
    const float* src;
    int off;
    if (flat < 524288)        { src = img; off = flat; }
    else if (flat < 1048576)  { src = aud; off = flat - 524288; }
    else                      { src = com; off = flat - 1048576; }
    float4 v = *(const float4*)(src + off);
    ush4 u = { f2b(v.x), f2b(v.y), f2b(v.z), f2b(v.w) };
    *(ush4*)(dst + idx4 * 4) = u;
  }
}

// 2) convert bil_w fp32 -> bf16
__global__ void k_cvt_bil(const float* __restrict__ bil, ushortT* __restrict__ dst) {
  int i4 = blockIdx.x * 256 + threadIdx.x;
#pragma unroll
  for (int q = 0; q < 8; q++) {
    int idx4 = i4 + q * 524288;
    float4 v = *(const float4*)(bil + idx4 * 4);
    ush4 u = { f2b(v.x), f2b(v.y), f2b(v.z), f2b(v.w) };
    *(ush4*)(dst + idx4 * 4) = u;
  }
}

// 3) transpose+convert
__global__ void k_transpose(const float* __restrict__ img, const float* __restrict__ aud,
                            const float* __restrict__ com,
                            const float* w0, const float* w1, const float* w2,
                            const float* w3, const float* w4, const float* w5,
                            const float* w6, const float* w7, const float* w8,
                            ushortT* __restrict__ actT, ushortT* __restrict__ wT) {
  __shared__ ushortT tl[64][72];
  int tid = threadIdx.x;
  int bx = blockIdx.x;
  const float* src;
  ushortT* dst;
  int R, C, r0, c0;
  if (bx < 384) {
    int inst = bx >> 5, tile = bx & 31;
    int act = inst >> 2, bb = inst & 3;
    src = (act == 0 ? img : (act == 1 ? aud : com)) + bb * 131072;
    dst = actT + act * 524288 + bb * 131072;
    R = 512; C = 256;
    r0 = (tile >> 2) * 64; c0 = (tile & 3) * 64;
  } else {
    int bw = bx - 384;
    int w = bw >> 4, tile = bw & 15;
    const float* s;
    switch (w) {
      case 0: s = w0; break; case 1: s = w1; break; case 2: s = w2; break;
      case 3: s = w3; break; case 4: s = w4; break; case 5: s = w5; break;
      case 6: s = w6; break; case 7: s = w7; break; default: s = w8; break;
    }
    src = s;
    dst = wT + w * 65536;
    R = 256; C = 256;
    r0 = (tile >> 2) * 64; c0 = (tile & 3) * 64;
  }
#pragma unroll
  for (int q = 0; q < 4; q++) {
    int rr = q * 16 + (tid >> 4);
    int cs = (tid & 15) * 4;
    float4 v = *(const float4*)(src + (r0 + rr) * C + c0 + cs);
    tl[rr][cs + 0] = f2b(v.x);
    tl[rr][cs + 1] = f2b(v.y);
    tl[rr][cs + 2] = f2b(v.z);
    tl[rr][cs + 3] = f2b(v.w);
  }
  __syncthreads();
#pragma unroll
  for (int q = 0; q < 4; q++) {
    int cc = q * 16 + (tid >> 4);
    int rs = (tid & 15) * 4;
    ush4 u = { tl[rs + 0][cc], tl[rs + 1][cc], tl[rs + 2][cc], tl[rs + 3][cc] };
    *(ush4*)(dst + (c0 + cc) * R + r0 + rs) = u;
  }
}

// =====================================================================
// 4) five input linears
__global__ __launch_bounds__(512) void k_linear5(
    const ushortT* __restrict__ act16, const ushortT* __restrict__ wT,
    const float* __restrict__ b0, const float* __restrict__ b1,
    const float* __restrict__ b2, const float* __restrict__ b3,
    const float* __restrict__ b4, ushortT* __restrict__ proj16) {
  __shared__ ushortT Al[4][32][8];
  __shared__ ushortT Bl[4][256][8];
  const int tid = threadIdx.x, l = tid & 63, w = tid >> 6;
  const int bx = blockIdx.x;
  const int op = bx >> 6, sblk = bx & 63;
  const int s0 = sblk * 32;
  const int xsel = (op == 4) ? 2 : (op & 1);
  const ushortT* X = act16 + xsel * ACT_E;
  const ushortT* W = wT + op * WD_E;
  const float* bias = op == 0 ? b0 : op == 1 ? b1 : op == 2 ? b2 : op == 3 ? b3 : b4;
  ushortT* out = proj16 + op * ACT_E;

  f32x4 acc[2][2] = {};
  ush8 ra, rb[2];
  int a_row = tid >> 2, a_seg = tid & 3;

  auto sload = [&](int k0) {
    if (tid < 128) ra = *(const ush8*)(X + (s0 + a_row) * 256 + k0 + a_seg * 8);
#pragma unroll
    for (int q = 0; q < 2; q++) {
      int slot = tid + q * 512;
      rb[q] = *(const ush8*)(W + (slot >> 2) * 256 + k0 + (slot & 3) * 8);
    }
  };
  auto swrite = [&]() {
    if (tid < 128) *(ush8*)(&Al[a_seg][a_row][0]) = ra;
#pragma unroll
    for (int q = 0; q < 2; q++) {
      int slot = tid + q * 512;
      *(ush8*)(&Bl[slot & 3][slot >> 2][0]) = rb[q];
    }
  };

  sload(0); swrite(); __syncthreads();
  for (int s = 0; s < 8; s++) {
    if (s < 7) sload((s + 1) * 32);
    int ks = l >> 4;
    bf16x8 a[2], bb[2];
#pragma unroll
    for (int m = 0; m < 2; m++) a[m] = *(const bf16x8*)(&Al[ks][m * 16 + (l & 15)][0]);
#pragma unroll
    for (int n = 0; n < 2; n++) bb[n] = *(const bf16x8*)(&Bl[ks][w * 32 + n * 16 + (l & 15)][0]);
#pragma unroll
    for (int m = 0; m < 2; m++)
#pragma unroll
      for (int n = 0; n < 2; n++) acc[m][n] = MFMA16(a[m], bb[n], acc[m][n]);
    if (s == 7) break;
    __syncthreads();
    swrite();
    __syncthreads();
  }
#pragma unroll
  for (int m = 0; m < 2; m++)
#pragma unroll
    for (int n = 0; n < 2; n++)
#pragma unroll
      for (int r = 0; r < 4; r++) {
        int row = s0 + m * 16 + (l >> 4) * 4 + r;
        int col = w * 32 + n * 16 + (l & 15);
        out[row * 256 + col] = f2b(acc[m][n][r] + bias[col]);
      }
}

// =====================================================================
// 5) attention: P = softmax(Q K^T) * (1/16)
__global__ __launch_bounds__(512) void k_attn(const ushortT* __restrict__ proj16,
                                              ushortT* __restrict__ P16) {
  __shared__ ushortT Ql[8][4][32][8];
  __shared__ ushortT Kl[4][512][8];
  __shared__ float red[32][8];
  const int tid = threadIdx.x, l = tid & 63, w = tid >> 6;
  const int bx = blockIdx.x;
  const int p = bx >> 6, b = (bx >> 4) & 3, sblk = bx & 15;
  const int s0 = sblk * 32;
  const int qsel = (p < 2) ? 0 : 1;
  const int ksel = (p == 0) ? 2 : (p == 2) ? 3 : 4;
  const ushortT* Q = proj16 + qsel * ACT_E + b * 131072;
  const ushortT* K = proj16 + ksel * ACT_E + b * 131072;
  ushortT* P = P16 + p * 1048576 + b * 262144;

#pragma unroll
  for (int q = 0; q < 2; q++) {
    int slot = tid + q * 512;
    int row = slot >> 5, seg = slot & 31;
    ush8 v = *(const ush8*)(Q + (s0 + row) * 256 + seg * 8);
    *(ush8*)(&Ql[seg >> 2][seg & 3][row][0]) = v;
  }

  f32x4 acc[2][4] = {};
  ush8 rk[4];
  auto kload = [&](int d0) {
#pragma unroll
    for (int q = 0; q < 4; q++) {
      int slot = tid + q * 512;
      rk[q] = *(const ush8*)(K + (slot >> 2) * 256 + d0 + (slot & 3) * 8);
    }
  };
  auto kwrite = [&]() {
#pragma unroll
    for (int q = 0; q < 4; q++) {
      int slot = tid + q * 512;
      *(ush8*)(&Kl[slot & 3][slot >> 2][0]) = rk[q];
    }
  };

  kload(0); kwrite(); __syncthreads();
  for (int s = 0; s < 8; s++) {
    if (s < 7) kload((s + 1) * 32);
    int ks = l >> 4;
    bf16x8 a[2], bb[4];
#pragma unroll
    for (int m = 0; m < 2; m++) a[m] = *(const bf16x8*)(&Ql[s][ks][m * 16 + (l & 15)][0]);
#pragma unroll
    for (int n = 0; n < 4; n++) bb[n] = *(const bf16x8*)(&Kl[ks][w * 64 + n * 16 + (l & 15)][0]);
#pragma unroll
    for (int m = 0; m < 2; m++)
#pragma unroll
      for (int n = 0; n < 4; n++) acc[m][n] = MFMA16(a[m], bb[n], acc[m][n]);
    if (s == 7) break;
    __syncthreads();
    kwrite();
    __syncthreads();
  }

  float gmax[2][4];
#pragma unroll
  for (int m = 0; m < 2; m++)
#pragma unroll
    for (int r = 0; r < 4; r++) {
      float v = fmaxf(fmaxf(acc[m][0][r], acc[m][1][r]), fmaxf(acc[m][2][r], acc[m][3][r]));
#pragma unroll
      for (int off = 1; off < 16; off <<= 1) v = fmaxf(v, __shfl_xor(v, off, 16));
      if ((l & 15) == 0) red[m * 16 + (l >> 4) * 4 + r][w] = v;
    }
  __syncthreads();
#pragma unroll
  for (int m = 0; m < 2; m++)
#pragma unroll
    for (int r = 0; r < 4; r++) {
      int sr = m * 16 + (l >> 4) * 4 + r;
      float g = red[sr][0];
#pragma unroll
      for (int ww = 1; ww < 8; ww++) g = fmaxf(g, red[sr][ww]);
      gmax[m][r] = g;
    }
  __syncthreads();
#pragma unroll
  for (int m = 0; m < 2; m++)
#pragma unroll
    for (int r = 0; r < 4; r++) {
      float ssum = 0.f;
#pragma unroll
      for (int n = 0; n < 4; n++) {
        float e = __expf(acc[m][n][r] - gmax[m][r]);
        acc[m][n][r] = e;
        ssum += e;
      }
#pragma unroll
      for (int off = 1; off < 16; off <<= 1) ssum += __shfl_xor(ssum, off, 16);
      if ((l & 15) == 0) red[m * 16 + (l >> 4) * 4 + r][w] = ssum;
    }
  __syncthreads();
#pragma unroll
  for (int m = 0; m < 2; m++)
#pragma unroll
    for (int r = 0; r < 4; r++) {
      int sr = m * 16 + (l >> 4) * 4 + r;
      float tot = 0.f;
#pragma unroll
      for (int ww = 0; ww < 8; ww++) tot += red[sr][ww];
      float sc = 0.0625f / tot;
#pragma unroll
      for (int n = 0; n < 4; n++)
        P[(s0 + sr) * 512 + w * 64 + n * 16 + (l & 15)] = f2b(acc[m][n][r] * sc);
    }
}

// =====================================================================
// 6) PV products
__global__ __launch_bounds__(512) void k_pv(const ushortT* __restrict__ P16,
                                            const ushortT* __restrict__ actT,
                                            float* __restrict__ pvv, float* __restrict__ pva,
                                            ushortT* __restrict__ vc16, ushortT* __restrict__ ac16) {
  __shared__ ushortT Al[4][32][8];
  __shared__ ushortT Bl[4][256][8];
  const int tid = threadIdx.x, l = tid & 63, w = tid >> 6;
  const int bx = blockIdx.x;
  const int p = bx >> 6, b = (bx >> 4) & 3, sblk = bx & 15;
  const int s0 = sblk * 32;
  const ushortT* A = P16 + p * 1048576 + b * 262144;
  const int vsel = (p == 0) ? 0 : (p == 2) ? 1 : 2;
  const ushortT* VT = actT + vsel * ACT_E + b * 131072;

  f32x4 acc[2][2] = {};
  ush8 ra, rb[2];
  int a_row = tid >> 2, a_seg = tid & 3;
  auto sload = [&](int t0) {
    if (tid < 128) ra = *(const ush8*)(A + (s0 + a_row) * 512 + t0 + a_seg * 8);
#pragma unroll
    for (int q = 0; q < 2; q++) {
      int slot = tid + q * 512;
      rb[q] = *(const ush8*)(VT + (slot >> 2) * 512 + t0 + (slot & 3) * 8);
    }
  };
  auto swrite = [&]() {
    if (tid < 128) *(ush8*)(&Al[a_seg][a_row][0]) = ra;
#pragma unroll
    for (int q = 0; q < 2; q++) {
      int slot = tid + q * 512;
      *(ush8*)(&Bl[slot & 3][slot >> 2][0]) = rb[q];
    }
  };

  sload(0); swrite(); __syncthreads();
  for (int s = 0; s < 16; s++) {
    if (s < 15) sload((s + 1) * 32);
    int ks = l >> 4;
    bf16x8 a[2], bb[2];
#pragma unroll
    for (int m = 0; m < 2; m++) a[m] = *(const bf16x8*)(&Al[ks][m * 16 + (l & 15)][0]);
#pragma unroll
    for (int n = 0; n < 2; n++) bb[n] = *(const bf16x8*)(&Bl[ks][w * 32 + n * 16 + (l & 15)][0]);
#pragma unroll
    for (int m = 0; m < 2; m++)
#pragma unroll
      for (int n = 0; n < 2; n++) acc[m][n] = MFMA16(a[m], bb[n], acc[m][n]);
    if (s == 15) break;
    __syncthreads();
    swrite();
    __syncthreads();
  }
#pragma unroll
  for (int m = 0; m < 2; m++)
#pragma unroll
    for (int n = 0; n < 2; n++)
#pragma unroll
      for (int r = 0; r < 4; r++) {
        int row = s0 + m * 16 + (l >> 4) * 4 + r;
        int col = w * 32 + n * 16 + (l & 15);
        int gi = (b * 512 + row) * 256 + col;
        float v = acc[m][n][r];
        if (p == 0) pvv[gi] = v;
        else if (p == 1) vc16[gi] = f2b(v);
        else if (p == 2) pva[gi] = v;
        else ac16[gi] = f2b(v);
      }
}

// =====================================================================
// 7) two linears + combine
__global__ __launch_bounds__(512) void k_lin4c(
    const ushortT* __restrict__ vc16, const ushortT* __restrict__ ac16,
    const ushortT* __restrict__ wT,
    const float* __restrict__ w5b, const float* __restrict__ w6b,
    const float* __restrict__ w7b, const float* __restrict__ w8b,
    const float* __restrict__ pvv, const float* __restrict__ pva,
    ushortT* __restrict__ cfv, ushortT* __restrict__ cfa) {
  __shared__ ushortT Al[4][32][8];
  __shared__ ushortT B1[4][256][8];
  __shared__ ushortT B2[4][256][8];
  const int tid = threadIdx.x, l = tid & 63, w = tid >> 6;
  const int bx = blockIdx.x;
  const int side = bx >> 6, sblk = bx & 63;
  const int s0 = sblk * 32;
  const ushortT* A = side ? ac16 : vc16;
  const ushortT* W1 = wT + (side ? 7 : 5) * WD_E;
  const ushortT* W2 = wT + (side ? 8 : 6) * WD_E;
  const float* bb1 = side ? w7b : w5b;
  const float* bb2 = side ? w8b : w6b;
  const float* pv = side ? pva : pvv;
  ushortT* out = side ? cfa : cfv;

  f32x4 acc1[2][2] = {}, acc2[2][2] = {};
  ush8 ra, rb1[2], rb2[2];
  int a_row = tid >> 2, a_seg = tid & 3;
  auto sload = [&](int k0) {
    if (tid < 128) ra = *(const ush8*)(A + (s0 + a_row) * 256 + k0 + a_seg * 8);
#pragma unroll
    for (int q = 0; q < 2; q++) {
      int slot = tid + q * 512;
      rb1[q] = *(const ush8*)(W1 + (slot >> 2) * 256 + k0 + (slot & 3) * 8);
      rb2[q] = *(const ush8*)(W2 + (slot >> 2) * 256 + k0 + (slot & 3) * 8);
    }
  };
  auto swrite = [&]() {
    if (tid < 128) *(ush8*)(&Al[a_seg][a_row][0]) = ra;
#pragma unroll
    for (int q = 0; q < 2; q++) {
      int slot = tid + q * 512;
      *(ush8*)(&B1[slot & 3][slot >> 2][0]) = rb1[q];
      *(ush8*)(&B2[slot & 3][slot >> 2][0]) = rb2[q];
    }
  };

  sload(0); swrite(); __syncthreads();
  for (int s = 0; s < 8; s++) {
    if (s < 7) sload((s + 1) * 32);
    int ks = l >> 4;
    bf16x8 a[2], x1[2], x2[2];
#pragma unroll
    for (int m = 0; m < 2; m++) a[m] = *(const bf16x8*)(&Al[ks][m * 16 + (l & 15)][0]);
#pragma unroll
    for (int n = 0; n < 2; n++) {
      x1[n] = *(const bf16x8*)(&B1[ks][w * 32 + n * 16 + (l & 15)][0]);
      x2[n] = *(const bf16x8*)(&B2[ks][w * 32 + n * 16 + (l & 15)][0]);
    }
#pragma unroll
    for (int m = 0; m < 2; m++)
#pragma unroll
      for (int n = 0; n < 2; n++) {
        acc1[m][n] = MFMA16(a[m], x1[n], acc1[m][n]);
        acc2[m][n] = MFMA16(a[m], x2[n], acc2[m][n]);
      }
    if (s == 7) break;
    __syncthreads();
    swrite();
    __syncthreads();
  }
#pragma unroll
  for (int m = 0; m < 2; m++)
#pragma unroll
    for (int n = 0; n < 2; n++)
#pragma unroll
      for (int r = 0; r < 4; r++) {
        int row = s0 + m * 16 + (l >> 4) * 4 + r;
        int col = w * 32 + n * 16 + (l & 15);
        int gi = row * 256 + col;
        float u1 = acc1[m][n][r] + bb1[col];
        float u2 = acc2[m][n][r] + bb2[col];
        out[gi] = f2b((1.f + u1) * pv[gi] + u2);
      }
}

// =====================================================================
// 8) bilinear v4: deep GEMM with i-fold, BK=64, dbuf, issue-early staging.
// m[r,ko] = sum_i cfv[r,i] * ( sum_j cfa[r,j] * W[ko, i*256+j] )
// grid 512 = ic(16) x mb(16) x nb(2), decoded via XCD-grouping swizzle.
// Block tile 128 rows x 128 ko, 256 threads (2x2 waves of 64x64).
// 64 K-steps of BK=64 (16 i x 4 j-steps). i-fold every 4 steps.
// Double-buffered LDS (2 x 32KB) + cfv f32 (8KB) = 72KB -> 2 blocks/CU.
// Stage(t+1) issued right after step-t barrier => vmcnt(0) at t+1 is a
// by-construction counted wait with a full compute-phase of slack.
__global__ __launch_bounds__(256, 2) void k_bilinear4(
    const ushortT* __restrict__ cfa, const ushortT* __restrict__ cfv,
    const ushortT* __restrict__ W, float* __restrict__ part) {
  // LDS arena: buf0 [0,32768), buf1 [32768,65536); each buf: A 16KB, B 16KB.
  // cfv f32 [128][16] @65536. Total 73728.
  __shared__ char arena[73728];
  const int tid = threadIdx.x, l = tid & 63, w = tid >> 6;
  // XCD-grouping swizzle: physical block d -> logical L so the 16 blocks
  // sharing a (ic,nb) W-panel land on the same XCD (assumes xcd = d%8).
  const int d = blockIdx.x;
  const int L = (d & 7) * 64 + (d >> 3);
  const int ic = L >> 5;          // 0..15
  const int nb = (L >> 4) & 1;    // 0..1
  const int mb = L & 15;          // 0..15
  const int r0 = mb * 128;
  const int ko0 = nb * 128;
  const int wr = w >> 1, wc = w & 1;   // 2x2 waves; wave tile 64x64

  // ---- cfv slice -> LDS fp32 [128][16]
  float* cfvl = (float*)(arena + 65536);
  {
    int row = tid >> 1, seg = tid & 1;
    ush8 v = *(const ush8*)(cfv + (r0 + row) * 256 + ic * 16 + seg * 8);
    float* dptr = cfvl + row * 16 + seg * 8;
#pragma unroll
    for (int q = 0; q < 8; q++) dptr[q] = b2f(v[q]);
  }
  __syncthreads();

  // ---- staging geometry ----
  // Tile layout (per region): [128 rows][64 cols bf16] = 128 B/row, 16 KB.
  // Physical byte p (linear, global_load_lds dest); logical l = p ^ ((p>>7&7)<<4);
  // row = l>>7, colbyte = l&127.  8 slots/thread: 0-3 -> A, 4-7 -> B.
  const char* gA[4];
  const char* gB[4];
#pragma unroll
  for (int s = 0; s < 4; s++) {
    int p = (tid + s * 256) * 16;              // 0..16383
    int lg = p ^ (((p >> 7) & 7) << 4);
    int row = lg >> 7, colb = lg & 127;
    gA[s] = (const char*)cfa + (size_t)(r0 + row) * 512 + colb;
    gB[s] = (const char*)W + (size_t)(ko0 + row) * 131072 + (size_t)ic * 8192 + colb;
  }

  // fragment read offsets (swizzled byte offsets within a 16KB region)
  int aoff0[4], aoff1[4], boff0[4], boff1[4];
#pragma unroll
  for (int m = 0; m < 4; m++) {
    int row = wr * 64 + m * 16 + (l & 15);
    int b0 = row * 128 + (l >> 4) * 16;
    int msk = (row & 7) << 4;
    aoff0[m] = b0 ^ msk;
    aoff1[m] = (b0 + 64) ^ msk;
  }
#pragma unroll
  for (int n = 0; n < 4; n++) {
    int row = wc * 64 + n * 16 + (l & 15);
    int b0 = row * 128 + (l >> 4) * 16;
    int msk = (row & 7) << 4;
    boff0[n] = b0 ^ msk;
    boff1[n] = (b0 + 64) ^ msk;
  }

  f32x4 macc[4][4] = {};
  f32x4 acci[4][4] = {};

  auto stage = [&](int t, char* bufbase) {
    int ja = (t & 3) << 7;   // A j-offset bytes (wraps every i)
    int jb = t << 7;         // B linear offset bytes
#pragma unroll
    for (int s = 0; s < 4; s++)
      async16(gA[s] + ja, bufbase + (tid + s * 256) * 16);
#pragma unroll
    for (int s = 0; s < 4; s++)
      async16(gB[s] + jb, bufbase + 16384 + (tid + s * 256) * 16);
  };

  // prologue: stage step 0 -> buf0
  stage(0, arena);

  int buf = 0;
  for (int t = 0; t < 64; t++) {
    asm volatile("s_waitcnt vmcnt(0)" ::: "memory");
    __builtin_amdgcn_s_barrier();

    char* Ab = arena + buf * 32768;
    char* Bb = Ab + 16384;

    // kc0 fragment reads
    bf16x8 a0[4], b0v[4];
#pragma unroll
    for (int m = 0; m < 4; m++) a0[m] = *(const bf16x8*)(Ab + aoff0[m]);
#pragma unroll
    for (int n = 0; n < 4; n++) b0v[n] = *(const bf16x8*)(Bb + boff0[n]);

    // issue next-step staging into the other buffer (WAR-safe: its readers
    // finished before the barrier above)
    if (t < 63) stage(t + 1, arena + (buf ^ 1) * 32768);

    __builtin_amdgcn_s_setprio(1);
#pragma unroll
    for (int m = 0; m < 4; m++)
#pragma unroll
      for (int n = 0; n < 4; n++) acci[m][n] = MFMA16(a0[m], b0v[n], acci[m][n]);
    __builtin_amdgcn_s_setprio(0);

    // kc1 fragment reads
    bf16x8 a1[4], b1v[4];
#pragma unroll
    for (int m = 0; m < 4; m++) a1[m] = *(const bf16x8*)(Ab + aoff1[m]);
#pragma unroll
    for (int n = 0; n < 4; n++) b1v[n] = *(const bf16x8*)(Bb + boff1[n]);

    __builtin_amdgcn_s_setprio(1);
#pragma unroll
    for (int m = 0; m < 4; m++)
#pragma unroll
      for (int n = 0; n < 4; n++) acci[m][n] = MFMA16(a1[m], b1v[n], acci[m][n]);
    __builtin_amdgcn_s_setprio(0);

    if ((t & 3) == 3) {
      int il = t >> 2;
#pragma unroll
      for (int m = 0; m < 4; m++) {
        int rbase = wr * 64 + m * 16 + ((l >> 4) << 2);
        float c0 = cfvl[(rbase + 0) * 16 + il];
        float c1 = cfvl[(rbase + 1) * 16 + il];
        float c2 = cfvl[(rbase + 2) * 16 + il];
        float c3 = cfvl[(rbase + 3) * 16 + il];
#pragma unroll
        for (int n = 0; n < 4; n++) {
          macc[m][n][0] += c0 * acci[m][n][0];
          macc[m][n][1] += c1 * acci[m][n][1];
          macc[m][n][2] += c2 * acci[m][n][2];
          macc[m][n][3] += c3 * acci[m][n][3];
          acci[m][n] = (f32x4){0.f, 0.f, 0.f, 0.f};
        }
      }
    }
    buf ^= 1;
  }

  // epilogue: store fp32 partial
  float* dst = part + (size_t)ic * 524288 + (size_t)r0 * 256 + ko0;
#pragma unroll
  for (int m = 0; m < 4; m++)
#pragma unroll
    for (int n = 0; n < 4; n++)
#pragma unroll
      for (int r = 0; r < 4; r++)
        dst[(wr * 64 + m * 16 + ((l >> 4) << 2) + r) * 256 + wc * 64 + n * 16 + (l & 15)] =
            macc[m][n][r];
}

// =====================================================================
// 9) final gate + partial reduction over 16 ic-chunks
__global__ void k_final2(const float* __restrict__ part, const float* __restrict__ img,
                         const float* __restrict__ aud, const float* __restrict__ t_o,
                         float* __restrict__ out0, float* __restrict__ out1) {
  int i = blockIdx.x * 256 + threadIdx.x;
  float t = t_o[0];
  float4 m = {0.f, 0.f, 0.f, 0.f};
#pragma unroll
  for (int ic = 0; ic < 16; ic++) {
    float4 p = ((const float4*)(part + ic * 524288))[i];
    m.x += p.x; m.y += p.y; m.z += p.z; m.w += p.w;
  }
  float4 a = ((const float4*)img)[i];
  float4 u = ((const float4*)aud)[i];
  float4 o0, o1;
  {
    float j = 1.f / (1.f + __expf(-m.x)); float Z = t * j * a.x + (1.f - j) * u.x;
    o0.x = Z + a.x; o1.x = Z + u.x;
  }
  {
    float j = 1.f / (1.f + __expf(-m.y)); float Z = t * j * a.y + (1.f - j) * u.y;
    o0.y = Z + a.y; o1.y = Z + u.y;
  }
  {
    float j = 1.f / (1.f + __expf(-m.z)); float Z = t * j * a.z + (1.f - j) * u.z;
    o0.z = Z + a.z; o1.z = Z + u.z;
  }
  {
    float j = 1.f / (1.f + __expf(-m.w)); float Z = t * j * a.w + (1.f - j) * u.w;
    o0.w = Z + a.w; o1.w = Z + u.w;
  }
  ((float4*)out0)[i] = o0;
  ((float4*)out1)[i] = o1;
}

// =====================================================================
extern "C" void kernel_launch(void* const* d_in, const int* in_sizes, int n_in,
                              void* d_out, int out_size, void* d_ws, size_t ws_size,
                              hipStream_t stream) {
  const float* img   = (const float*)d_in[0];
  const float* aud   = (const float*)d_in[1];
  const float* com   = (const float*)d_in[2];
  const float* qv_w  = (const float*)d_in[3];
  const float* qv_b  = (const float*)d_in[4];
  const float* qa_w  = (const float*)d_in[5];
  const float* qa_b  = (const float*)d_in[6];
  const float* kv_w  = (const float*)d_in[7];
  const float* kv_b  = (const float*)d_in[8];
  const float* ka_w  = (const float*)d_in[9];
  const float* ka_b  = (const float*)d_in[10];
  const float* cc_w  = (const float*)d_in[11];
  const float* cc_b  = (const float*)d_in[12];
  const float* w5_w  = (const float*)d_in[13];
  const float* w5_b  = (const float*)d_in[14];
  const float* w6_w  = (const float*)d_in[15];
  const float* w6_b  = (const float*)d_in[16];
  const float* w7_w  = (const float*)d_in[17];
  const float* w7_b  = (const float*)d_in[18];
  const float* w8_w  = (const float*)d_in[19];
  const float* w8_b  = (const float*)d_in[20];
  const float* bil_w = (const float*)d_in[21];
  const float* t_o   = (const float*)d_in[22];
  float* out = (float*)d_out;

  char* ws = (char*)d_ws;
  ushortT* act16  = (ushortT*)(ws + OFF_ACT16);
  ushortT* actT16 = (ushortT*)(ws + OFF_ACTT16);
  ushortT* w16t   = (ushortT*)(ws + OFF_W16T);
  ushortT* proj16 = (ushortT*)(ws + OFF_PROJ16);
  ushortT* P16    = (ushortT*)(ws + OFF_P16);
  ushortT* vc16   = (ushortT*)(ws + OFF_VC16);
  ushortT* ac16   = (ushortT*)(ws + OFF_AC16);
  float*   pvv32  = (float*)(ws + OFF_PVV32);
  float*   pva32  = (float*)(ws + OFF_PVA32);
  float*   part   = (float*)(ws + OFF_PART);
  ushortT* bil16  = (ushortT*)(ws + OFF_BIL16);
  ushortT* cfv16  = (ushortT*)(ws + OFF_CFV16);
  ushortT* cfa16  = (ushortT*)(ws + OFF_CFA16);

  k_cvt_acts<<<384, 256, 0, stream>>>(img, aud, com, act16);
  k_cvt_bil<<<2048, 256, 0, stream>>>(bil_w, bil16);
  k_transpose<<<528, 256, 0, stream>>>(img, aud, com, qv_w, qa_w, kv_w, ka_w, cc_w,
                                       w5_w, w6_w, w7_w, w8_w, actT16, w16t);
  k_linear5<<<320, 512, 0, stream>>>(act16, w16t, qv_b, qa_b, kv_b, ka_b, cc_b, proj16);
  k_attn<<<256, 512, 0, stream>>>(proj16, P16);
  k_pv<<<256, 512, 0, stream>>>(P16, actT16, pvv32, pva32, vc16, ac16);
  k_lin4c<<<128, 512, 0, stream>>>(vc16, ac16, w16t, w5_b, w6_b, w7_b, w8_b,
                                   pvv32, pva32, cfv16, cfa16);
  k_bilinear4<<<512, 256, 0, stream>>>(cfa16, cfv16, bil16, part);
  k_final2<<<512, 256, 0, stream>>>(part, img, aud, t_o, out, out + 524288);
}

// Round 5
// 150.843 us; speedup vs baseline: 1.0606x; 1.0164x over previous
//
#include <hip/hip_runtime.h>
#include <hip/hip_bf16.h>

// ---------- types ----------
typedef unsigned short ushortT;
typedef __bf16 bf16x8 __attribute__((ext_vector_type(8)));
typedef float f32x4 __attribute__((ext_vector_type(4)));
typedef ushortT ush8 __attribute__((ext_vector_type(8)));
typedef ushortT ush4 __attribute__((ext_vector_type(4)));

#define MFMA16(a, b, c) __builtin_amdgcn_mfma_f32_16x16x32_bf16((a), (b), (c), 0, 0, 0)

__device__ __forceinline__ ushortT f2b(float f) {
  __hip_bfloat16 h = __float2bfloat16(f);
  return __builtin_bit_cast(ushortT, h);
}
__device__ __forceinline__ float b2f(ushortT u) {
  __hip_bfloat16 h = __builtin_bit_cast(__hip_bfloat16, u);
  return __bfloat162float(h);
}

// async global->LDS, 16B per lane
__device__ __forceinline__ void async16(const void* g, void* l) {
  __builtin_amdgcn_global_load_lds((const __attribute__((address_space(1))) unsigned int*)g,
                                   (__attribute__((address_space(3))) unsigned int*)l, 16, 0, 0);
}

// ---------- problem dims ----------
// B=4, S=512, D=256, ROWS = B*S = 2048
#define ACT_E 524288   // 2048*256 elements
#define WD_E  65536    // 256*256

// ---------- ws layout (bytes) ----------
#define OFF_ACT16   0u          // 3 * ACT_E * 2 = 3145728
#define OFF_ACTT16  3145728u    // 3 * ACT_E * 2
#define OFF_W16T    6291456u    // 9 * WD_E * 2 = 1179648
#define OFF_PROJ16  7471104u    // 5 * ACT_E * 2 = 5242880
#define OFF_P16     12713984u   // 4 * 1048576 * 2 = 8388608
#define OFF_VC16    21102592u   // ACT_E*2
#define OFF_AC16    22151168u
#define OFF_PVV32   23199744u   // ACT_E*4
#define OFF_PVA32   25296896u   // ends 27394048
#define OFF_PART    0u          // 16 * 2048*256*4 = 33554432 (overlaps transients)
#define OFF_BIL16   33554432u   // 16777216*2 = 33554432, ends 67108864
#define OFF_CFV16   67108864u   // ACT_E*2
#define OFF_CFA16   68157440u   // ends 69206016

// =====================================================================
// 1) convert img/audio/common fp32 -> bf16 (same layout)
__global__ void k_cvt_acts(const float* __restrict__ img, const float* __restrict__ aud,
                           const float* __restrict__ com, ushortT* __restrict__ dst) {
  int i4 = blockIdx.x * 256 + threadIdx.x;
#pragma unroll
  for (int q = 0; q < 4; q++) {
    int idx4 = i4 + q * 98304;
    int flat = idx4 * 4;
    const float* src;
    int off;
    if (flat < 524288)        { src = img; off = flat; }
    else if (flat < 1048576)  { src = aud; off = flat - 524288; }
    else                      { src = com; off = flat - 1048576; }
    float4 v = *(const float4*)(src + off);
    ush4 u = { f2b(v.x), f2b(v.y), f2b(v.z), f2b(v.w) };
    *(ush4*)(dst + idx4 * 4) = u;
  }
}

// 2) convert bil_w fp32 -> bf16
__global__ void k_cvt_bil(const float* __restrict__ bil, ushortT* __restrict__ dst) {
  int i4 = blockIdx.x * 256 + threadIdx.x;
#pragma unroll
  for (int q = 0; q < 8; q++) {
    int idx4 = i4 + q * 524288;
    float4 v = *(const float4*)(bil + idx4 * 4);
    ush4 u = { f2b(v.x), f2b(v.y), f2b(v.z), f2b(v.w) };
    *(ush4*)(dst + idx4 * 4) = u;
  }
}

// 3) transpose+convert
__global__ void k_transpose(const float* __restrict__ img, const float* __restrict__ aud,
                            const float* __restrict__ com,
                            const float* w0, const float* w1, const float* w2,
                            const float* w3, const float* w4, const float* w5,
                            const float* w6, const float* w7, const float* w8,
                            ushortT* __restrict__ actT, ushortT* __restrict__ wT) {
  __shared__ ushortT tl[64][72];
  int tid = threadIdx.x;
  int bx = blockIdx.x;
  const float* src;
  ushortT* dst;
  int R, C, r0, c0;
  if (bx < 384) {
    int inst = bx >> 5, tile = bx & 31;
    int act = inst >> 2, bb = inst & 3;
    src = (act == 0 ? img : (act == 1 ? aud : com)) + bb * 131072;
    dst = actT + act * 524288 + bb * 131072;
    R = 512; C = 256;
    r0 = (tile >> 2) * 64; c0 = (tile & 3) * 64;
  } else {
    int bw = bx - 384;
    int w = bw >> 4, tile = bw & 15;
    const float* s;
    switch (w) {
      case 0: s = w0; break; case 1: s = w1; break; case 2: s = w2; break;
      case 3: s = w3; break; case 4: s = w4; break; case 5: s = w5; break;
      case 6: s = w6; break; case 7: s = w7; break; default: s = w8; break;
    }
    src = s;
    dst = wT + w * 65536;
    R = 256; C = 256;
    r0 = (tile >> 2) * 64; c0 = (tile & 3) * 64;
  }
#pragma unroll
  for (int q = 0; q < 4; q++) {
    int rr = q * 16 + (tid >> 4);
    int cs = (tid & 15) * 4;
    float4 v = *(const float4*)(src + (r0 + rr) * C + c0 + cs);
    tl[rr][cs + 0] = f2b(v.x);
    tl[rr][cs + 1] = f2b(v.y);
    tl[rr][cs + 2] = f2b(v.z);
    tl[rr][cs + 3] = f2b(v.w);
  }
  __syncthreads();
#pragma unroll
  for (int q = 0; q < 4; q++) {
    int cc = q * 16 + (tid >> 4);
    int rs = (tid & 15) * 4;
    ush4 u = { tl[rs + 0][cc], tl[rs + 1][cc], tl[rs + 2][cc], tl[rs + 3][cc] };
    *(ush4*)(dst + (c0 + cc) * R + r0 + rs) = u;
  }
}

// =====================================================================
// 4) five input linears
__global__ __launch_bounds__(512) void k_linear5(
    const ushortT* __restrict__ act16, const ushortT* __restrict__ wT,
    const float* __restrict__ b0, const float* __restrict__ b1,
    const float* __restrict__ b2, const float* __restrict__ b3,
    const float* __restrict__ b4, ushortT* __restrict__ proj16) {
  __shared__ ushortT Al[4][32][8];
  __shared__ ushortT Bl[4][256][8];
  const int tid = threadIdx.x, l = tid & 63, w = tid >> 6;
  const int bx = blockIdx.x;
  const int op = bx >> 6, sblk = bx & 63;
  const int s0 = sblk * 32;
  const int xsel = (op == 4) ? 2 : (op & 1);
  const ushortT* X = act16 + xsel * ACT_E;
  const ushortT* W = wT + op * WD_E;
  const float* bias = op == 0 ? b0 : op == 1 ? b1 : op == 2 ? b2 : op == 3 ? b3 : b4;
  ushortT* out = proj16 + op * ACT_E;

  f32x4 acc[2][2] = {};
  ush8 ra, rb[2];
  int a_row = tid >> 2, a_seg = tid & 3;

  auto sload = [&](int k0) {
    if (tid < 128) ra = *(const ush8*)(X + (s0 + a_row) * 256 + k0 + a_seg * 8);
#pragma unroll
    for (int q = 0; q < 2; q++) {
      int slot = tid + q * 512;
      rb[q] = *(const ush8*)(W + (slot >> 2) * 256 + k0 + (slot & 3) * 8);
    }
  };
  auto swrite = [&]() {
    if (tid < 128) *(ush8*)(&Al[a_seg][a_row][0]) = ra;
#pragma unroll
    for (int q = 0; q < 2; q++) {
      int slot = tid + q * 512;
      *(ush8*)(&Bl[slot & 3][slot >> 2][0]) = rb[q];
    }
  };

  sload(0); swrite(); __syncthreads();
  for (int s = 0; s < 8; s++) {
    if (s < 7) sload((s + 1) * 32);
    int ks = l >> 4;
    bf16x8 a[2], bb[2];
#pragma unroll
    for (int m = 0; m < 2; m++) a[m] = *(const bf16x8*)(&Al[ks][m * 16 + (l & 15)][0]);
#pragma unroll
    for (int n = 0; n < 2; n++) bb[n] = *(const bf16x8*)(&Bl[ks][w * 32 + n * 16 + (l & 15)][0]);
#pragma unroll
    for (int m = 0; m < 2; m++)
#pragma unroll
      for (int n = 0; n < 2; n++) acc[m][n] = MFMA16(a[m], bb[n], acc[m][n]);
    if (s == 7) break;
    __syncthreads();
    swrite();
    __syncthreads();
  }
#pragma unroll
  for (int m = 0; m < 2; m++)
#pragma unroll
    for (int n = 0; n < 2; n++)
#pragma unroll
      for (int r = 0; r < 4; r++) {
        int row = s0 + m * 16 + (l >> 4) * 4 + r;
        int col = w * 32 + n * 16 + (l & 15);
        out[row * 256 + col] = f2b(acc[m][n][r] + bias[col]);
      }
}

// =====================================================================
// 5) attention: P = softmax(Q K^T) * (1/16)
__global__ __launch_bounds__(512) void k_attn(const ushortT* __restrict__ proj16,
                                              ushortT* __restrict__ P16) {
  __shared__ ushortT Ql[8][4][32][8];
  __shared__ ushortT Kl[4][512][8];
  __shared__ float red[32][8];
  const int tid = threadIdx.x, l = tid & 63, w = tid >> 6;
  const int bx = blockIdx.x;
  const int p = bx >> 6, b = (bx >> 4) & 3, sblk = bx & 15;
  const int s0 = sblk * 32;
  const int qsel = (p < 2) ? 0 : 1;
  const int ksel = (p == 0) ? 2 : (p == 2) ? 3 : 4;
  const ushortT* Q = proj16 + qsel * ACT_E + b * 131072;
  const ushortT* K = proj16 + ksel * ACT_E + b * 131072;
  ushortT* P = P16 + p * 1048576 + b * 262144;

#pragma unroll
  for (int q = 0; q < 2; q++) {
    int slot = tid + q * 512;
    int row = slot >> 5, seg = slot & 31;
    ush8 v = *(const ush8*)(Q + (s0 + row) * 256 + seg * 8);
    *(ush8*)(&Ql[seg >> 2][seg & 3][row][0]) = v;
  }

  f32x4 acc[2][4] = {};
  ush8 rk[4];
  auto kload = [&](int d0) {
#pragma unroll
    for (int q = 0; q < 4; q++) {
      int slot = tid + q * 512;
      rk[q] = *(const ush8*)(K + (slot >> 2) * 256 + d0 + (slot & 3) * 8);
    }
  };
  auto kwrite = [&]() {
#pragma unroll
    for (int q = 0; q < 4; q++) {
      int slot = tid + q * 512;
      *(ush8*)(&Kl[slot & 3][slot >> 2][0]) = rk[q];
    }
  };

  kload(0); kwrite(); __syncthreads();
  for (int s = 0; s < 8; s++) {
    if (s < 7) kload((s + 1) * 32);
    int ks = l >> 4;
    bf16x8 a[2], bb[4];
#pragma unroll
    for (int m = 0; m < 2; m++) a[m] = *(const bf16x8*)(&Ql[s][ks][m * 16 + (l & 15)][0]);
#pragma unroll
    for (int n = 0; n < 4; n++) bb[n] = *(const bf16x8*)(&Kl[ks][w * 64 + n * 16 + (l & 15)][0]);
#pragma unroll
    for (int m = 0; m < 2; m++)
#pragma unroll
      for (int n = 0; n < 4; n++) acc[m][n] = MFMA16(a[m], bb[n], acc[m][n]);
    if (s == 7) break;
    __syncthreads();
    kwrite();
    __syncthreads();
  }

  float gmax[2][4];
#pragma unroll
  for (int m = 0; m < 2; m++)
#pragma unroll
    for (int r = 0; r < 4; r++) {
      float v = fmaxf(fmaxf(acc[m][0][r], acc[m][1][r]), fmaxf(acc[m][2][r], acc[m][3][r]));
#pragma unroll
      for (int off = 1; off < 16; off <<= 1) v = fmaxf(v, __shfl_xor(v, off, 16));
      if ((l & 15) == 0) red[m * 16 + (l >> 4) * 4 + r][w] = v;
    }
  __syncthreads();
#pragma unroll
  for (int m = 0; m < 2; m++)
#pragma unroll
    for (int r = 0; r < 4; r++) {
      int sr = m * 16 + (l >> 4) * 4 + r;
      float g = red[sr][0];
#pragma unroll
      for (int ww = 1; ww < 8; ww++) g = fmaxf(g, red[sr][ww]);
      gmax[m][r] = g;
    }
  __syncthreads();
#pragma unroll
  for (int m = 0; m < 2; m++)
#pragma unroll
    for (int r = 0; r < 4; r++) {
      float ssum = 0.f;
#pragma unroll
      for (int n = 0; n < 4; n++) {
        float e = __expf(acc[m][n][r] - gmax[m][r]);
        acc[m][n][r] = e;
        ssum += e;
      }
#pragma unroll
      for (int off = 1; off < 16; off <<= 1) ssum += __shfl_xor(ssum, off, 16);
      if ((l & 15) == 0) red[m * 16 + (l >> 4) * 4 + r][w] = ssum;
    }
  __syncthreads();
#pragma unroll
  for (int m = 0; m < 2; m++)
#pragma unroll
    for (int r = 0; r < 4; r++) {
      int sr = m * 16 + (l >> 4) * 4 + r;
      float tot = 0.f;
#pragma unroll
      for (int ww = 0; ww < 8; ww++) tot += red[sr][ww];
      float sc = 0.0625f / tot;
#pragma unroll
      for (int n = 0; n < 4; n++)
        P[(s0 + sr) * 512 + w * 64 + n * 16 + (l & 15)] = f2b(acc[m][n][r] * sc);
    }
}

// =====================================================================
// 6) PV products
__global__ __launch_bounds__(512) void k_pv(const ushortT* __restrict__ P16,
                                            const ushortT* __restrict__ actT,
                                            float* __restrict__ pvv, float* __restrict__ pva,
                                            ushortT* __restrict__ vc16, ushortT* __restrict__ ac16) {
  __shared__ ushortT Al[4][32][8];
  __shared__ ushortT Bl[4][256][8];
  const int tid = threadIdx.x, l = tid & 63, w = tid >> 6;
  const int bx = blockIdx.x;
  const int p = bx >> 6, b = (bx >> 4) & 3, sblk = bx & 15;
  const int s0 = sblk * 32;
  const ushortT* A = P16 + p * 1048576 + b * 262144;
  const int vsel = (p == 0) ? 0 : (p == 2) ? 1 : 2;
  const ushortT* VT = actT + vsel * ACT_E + b * 131072;

  f32x4 acc[2][2] = {};
  ush8 ra, rb[2];
  int a_row = tid >> 2, a_seg = tid & 3;
  auto sload = [&](int t0) {
    if (tid < 128) ra = *(const ush8*)(A + (s0 + a_row) * 512 + t0 + a_seg * 8);
#pragma unroll
    for (int q = 0; q < 2; q++) {
      int slot = tid + q * 512;
      rb[q] = *(const ush8*)(VT + (slot >> 2) * 512 + t0 + (slot & 3) * 8);
    }
  };
  auto swrite = [&]() {
    if (tid < 128) *(ush8*)(&Al[a_seg][a_row][0]) = ra;
#pragma unroll
    for (int q = 0; q < 2; q++) {
      int slot = tid + q * 512;
      *(ush8*)(&Bl[slot & 3][slot >> 2][0]) = rb[q];
    }
  };

  sload(0); swrite(); __syncthreads();
  for (int s = 0; s < 16; s++) {
    if (s < 15) sload((s + 1) * 32);
    int ks = l >> 4;
    bf16x8 a[2], bb[2];
#pragma unroll
    for (int m = 0; m < 2; m++) a[m] = *(const bf16x8*)(&Al[ks][m * 16 + (l & 15)][0]);
#pragma unroll
    for (int n = 0; n < 2; n++) bb[n] = *(const bf16x8*)(&Bl[ks][w * 32 + n * 16 + (l & 15)][0]);
#pragma unroll
    for (int m = 0; m < 2; m++)
#pragma unroll
      for (int n = 0; n < 2; n++) acc[m][n] = MFMA16(a[m], bb[n], acc[m][n]);
    if (s == 15) break;
    __syncthreads();
    swrite();
    __syncthreads();
  }
#pragma unroll
  for (int m = 0; m < 2; m++)
#pragma unroll
    for (int n = 0; n < 2; n++)
#pragma unroll
      for (int r = 0; r < 4; r++) {
        int row = s0 + m * 16 + (l >> 4) * 4 + r;
        int col = w * 32 + n * 16 + (l & 15);
        int gi = (b * 512 + row) * 256 + col;
        float v = acc[m][n][r];
        if (p == 0) pvv[gi] = v;
        else if (p == 1) vc16[gi] = f2b(v);
        else if (p == 2) pva[gi] = v;
        else ac16[gi] = f2b(v);
      }
}

// =====================================================================
// 7) two linears + combine
__global__ __launch_bounds__(512) void k_lin4c(
    const ushortT* __restrict__ vc16, const ushortT* __restrict__ ac16,
    const ushortT* __restrict__ wT,
    const float* __restrict__ w5b, const float* __restrict__ w6b,
    const float* __restrict__ w7b, const float* __restrict__ w8b,
    const float* __restrict__ pvv, const float* __restrict__ pva,
    ushortT* __restrict__ cfv, ushortT* __restrict__ cfa) {
  __shared__ ushortT Al[4][32][8];
  __shared__ ushortT B1[4][256][8];
  __shared__ ushortT B2[4][256][8];
  const int tid = threadIdx.x, l = tid & 63, w = tid >> 6;
  const int bx = blockIdx.x;
  const int side = bx >> 6, sblk = bx & 63;
  const int s0 = sblk * 32;
  const ushortT* A = side ? ac16 : vc16;
  const ushortT* W1 = wT + (side ? 7 : 5) * WD_E;
  const ushortT* W2 = wT + (side ? 8 : 6) * WD_E;
  const float* bb1 = side ? w7b : w5b;
  const float* bb2 = side ? w8b : w6b;
  const float* pv = side ? pva : pvv;
  ushortT* out = side ? cfa : cfv;

  f32x4 acc1[2][2] = {}, acc2[2][2] = {};
  ush8 ra, rb1[2], rb2[2];
  int a_row = tid >> 2, a_seg = tid & 3;
  auto sload = [&](int k0) {
    if (tid < 128) ra = *(const ush8*)(A + (s0 + a_row) * 256 + k0 + a_seg * 8);
#pragma unroll
    for (int q = 0; q < 2; q++) {
      int slot = tid + q * 512;
      rb1[q] = *(const ush8*)(W1 + (slot >> 2) * 256 + k0 + (slot & 3) * 8);
      rb2[q] = *(const ush8*)(W2 + (slot >> 2) * 256 + k0 + (slot & 3) * 8);
    }
  };
  auto swrite = [&]() {
    if (tid < 128) *(ush8*)(&Al[a_seg][a_row][0]) = ra;
#pragma unroll
    for (int q = 0; q < 2; q++) {
      int slot = tid + q * 512;
      *(ush8*)(&B1[slot & 3][slot >> 2][0]) = rb1[q];
      *(ush8*)(&B2[slot & 3][slot >> 2][0]) = rb2[q];
    }
  };

  sload(0); swrite(); __syncthreads();
  for (int s = 0; s < 8; s++) {
    if (s < 7) sload((s + 1) * 32);
    int ks = l >> 4;
    bf16x8 a[2], x1[2], x2[2];
#pragma unroll
    for (int m = 0; m < 2; m++) a[m] = *(const bf16x8*)(&Al[ks][m * 16 + (l & 15)][0]);
#pragma unroll
    for (int n = 0; n < 2; n++) {
      x1[n] = *(const bf16x8*)(&B1[ks][w * 32 + n * 16 + (l & 15)][0]);
      x2[n] = *(const bf16x8*)(&B2[ks][w * 32 + n * 16 + (l & 15)][0]);
    }
#pragma unroll
    for (int m = 0; m < 2; m++)
#pragma unroll
      for (int n = 0; n < 2; n++) {
        acc1[m][n] = MFMA16(a[m], x1[n], acc1[m][n]);
        acc2[m][n] = MFMA16(a[m], x2[n], acc2[m][n]);
      }
    if (s == 7) break;
    __syncthreads();
    swrite();
    __syncthreads();
  }
#pragma unroll
  for (int m = 0; m < 2; m++)
#pragma unroll
    for (int n = 0; n < 2; n++)
#pragma unroll
      for (int r = 0; r < 4; r++) {
        int row = s0 + m * 16 + (l >> 4) * 4 + r;
        int col = w * 32 + n * 16 + (l & 15);
        int gi = row * 256 + col;
        float u1 = acc1[m][n][r] + bb1[col];
        float u2 = acc2[m][n][r] + bb2[col];
        out[gi] = f2b((1.f + u1) * pv[gi] + u2);
      }
}

// =====================================================================
// 8) bilinear v5: 8-wave block, depth-3 pipeline, counted vmcnt(6).
// m[r,ko] = sum_i cfv[r,i] * ( sum_j cfa[r,j] * W[ko, i*256+j] )
// grid 256 = ic(16) x mb(8) x nb(2), XCD-grouped.  Block tile 256 rows x
// 128 ko, 512 threads (4Mx2N waves of 64x64).  64 K-steps of BK=64
// (16 i x 4 j-steps); i-fold every 4 steps.  3 LDS buffers; stage(t+2)
// issued mid-step; per-step wait = vmcnt(6) (loads stay in flight across
// the barrier - only the last two steps drain).  setprio(1) around MFMA.
__global__ __launch_bounds__(512, 2) void k_bilinear5(
    const ushortT* __restrict__ cfa, const ushortT* __restrict__ cfv,
    const ushortT* __restrict__ W, float* __restrict__ part) {
  // LDS: A 3x32768 @0; B 3x16384 @98304; cfv bf16 [256][16] @147456. tot 155648
  __shared__ char arena[155648];
  const int tid = threadIdx.x, l = tid & 63, w = tid >> 6;
  // XCD-grouping: the 8 mb-blocks sharing a (ic,nb) W-panel land on one XCD.
  const int d = blockIdx.x;
  const int L = (d & 7) * 32 + (d >> 3);
  const int ic = L >> 4;          // 0..15
  const int mb = (L >> 1) & 7;    // 0..7
  const int nb = L & 1;           // 0..1
  const int r0 = mb * 256;
  const int ko0 = nb * 128;
  const int wr = w >> 1, wc = w & 1;   // 4(M) x 2(N) waves; wave tile 64x64

  // ---- cfv slice -> LDS bf16 [256][16]
  ushortT* cfvl = (ushortT*)(arena + 147456);
  {
    int row = tid >> 1, seg = tid & 1;
    *(ush8*)(cfvl + row * 16 + seg * 8) =
        *(const ush8*)(cfv + (r0 + row) * 256 + ic * 16 + seg * 8);
  }
  __syncthreads();

  // ---- staging geometry (A: 4 slots, B: 2 slots per thread) ----
  // Tiles: A [256 rows][64 j] bf16 = 128B/row, 32KB. B [128 ko][64 j] = 16KB.
  // phys byte p -> logical lg = p ^ ((p>>7 & 7)<<4); row = lg>>7, colb = lg&127.
  const char* gA[4];
  const char* gB[2];
#pragma unroll
  for (int s = 0; s < 4; s++) {
    int p = (tid + s * 512) * 16;
    int lg = p ^ (((p >> 7) & 7) << 4);
    gA[s] = (const char*)cfa + (size_t)(r0 + (lg >> 7)) * 512 + (lg & 127);
  }
#pragma unroll
  for (int s = 0; s < 2; s++) {
    int p = (tid + s * 512) * 16;
    int lg = p ^ (((p >> 7) & 7) << 4);
    gB[s] = (const char*)W + (size_t)(ko0 + (lg >> 7)) * 131072 + (size_t)ic * 8192 + (lg & 127);
  }

  auto stage = [&](int t) {
    char* Ab = arena + (t % 3) * 32768;
    char* Bb = arena + 98304 + (t % 3) * 16384;
    int ja = (t & 3) << 7;     // A j-offset bytes (period 4)
    int jb = t << 7;           // B offset bytes (linear in t: i*8192/4 steps)
#pragma unroll
    for (int s = 0; s < 4; s++) async16(gA[s] + ja, Ab + (tid + s * 512) * 16);
#pragma unroll
    for (int s = 0; s < 2; s++) async16(gB[s] + jb, Bb + (tid + s * 512) * 16);
  };

  // fragment read offsets (swizzled bytes within a tile), per kc half
  int aoff[2][4], boff[2][4];
#pragma unroll
  for (int m = 0; m < 4; m++) {
    int row = wr * 64 + m * 16 + (l & 15);
    int b0 = row * 128 + (l >> 4) * 16;
    int msk = (row & 7) << 4;
    aoff[0][m] = b0 ^ msk;
    aoff[1][m] = (b0 + 64) ^ msk;
  }
#pragma unroll
  for (int n = 0; n < 4; n++) {
    int row = wc * 64 + n * 16 + (l & 15);
    int b0 = row * 128 + (l >> 4) * 16;
    int msk = (row & 7) << 4;
    boff[0][n] = b0 ^ msk;
    boff[1][n] = (b0 + 64) ^ msk;
  }

  f32x4 macc[4][4] = {};
  f32x4 acci[4][4] = {};

  // prologue: two steps staged ahead
  stage(0);
  stage(1);

  for (int t = 0; t < 64; t++) {
    // counted wait: step t's 6 loads are the oldest; t+1/t+2's may stay in flight
    if (t < 62) asm volatile("s_waitcnt vmcnt(6)" ::: "memory");
    else        asm volatile("s_waitcnt vmcnt(0)" ::: "memory");
    __builtin_amdgcn_s_barrier();

    char* Ab = arena + (t % 3) * 32768;
    char* Bb = arena + 98304 + (t % 3) * 16384;

    // kc0
    bf16x8 a0[4], b0v[4];
#pragma unroll
    for (int m = 0; m < 4; m++) a0[m] = *(const bf16x8*)(Ab + aoff[0][m]);
#pragma unroll
    for (int n = 0; n < 4; n++) b0v[n] = *(const bf16x8*)(Bb + boff[0][n]);
    __builtin_amdgcn_s_setprio(1);
#pragma unroll
    for (int m = 0; m < 4; m++)
#pragma unroll
      for (int n = 0; n < 4; n++) acci[m][n] = MFMA16(a0[m], b0v[n], acci[m][n]);
    __builtin_amdgcn_s_setprio(0);

    // issue stage(t+2) between the two MFMA clusters (WAR-safe: the buffer it
    // overwrites was last read in step t-1, and every wave passed the top-of-t
    // barrier before this point)
    if (t + 2 < 64) stage(t + 2);

    // kc1
    bf16x8 a1[4], b1v[4];
#pragma unroll
    for (int m = 0; m < 4; m++) a1[m] = *(const bf16x8*)(Ab + aoff[1][m]);
#pragma unroll
    for (int n = 0; n < 4; n++) b1v[n] = *(const bf16x8*)(Bb + boff[1][n]);
    __builtin_amdgcn_s_setprio(1);
#pragma unroll
    for (int m = 0; m < 4; m++)
#pragma unroll
      for (int n = 0; n < 4; n++) acci[m][n] = MFMA16(a1[m], b1v[n], acci[m][n]);
    __builtin_amdgcn_s_setprio(0);

    // i-fold every 4 steps
    if ((t & 3) == 3) {
      int il = t >> 2;
#pragma unroll
      for (int m = 0; m < 4; m++) {
        int rbase = wr * 64 + m * 16 + ((l >> 4) << 2);
        float c0 = b2f(cfvl[(rbase + 0) * 16 + il]);
        float c1 = b2f(cfvl[(rbase + 1) * 16 + il]);
        float c2 = b2f(cfvl[(rbase + 2) * 16 + il]);
        float c3 = b2f(cfvl[(rbase + 3) * 16 + il]);
#pragma unroll
        for (int n = 0; n < 4; n++) {
          macc[m][n][0] += c0 * acci[m][n][0];
          macc[m][n][1] += c1 * acci[m][n][1];
          macc[m][n][2] += c2 * acci[m][n][2];
          macc[m][n][3] += c3 * acci[m][n][3];
          acci[m][n] = (f32x4){0.f, 0.f, 0.f, 0.f};
        }
      }
    }
  }

  // epilogue: store fp32 partial
  float* dst = part + (size_t)ic * 524288 + (size_t)r0 * 256 + ko0;
#pragma unroll
  for (int m = 0; m < 4; m++)
#pragma unroll
    for (int n = 0; n < 4; n++)
#pragma unroll
      for (int r = 0; r < 4; r++)
        dst[(wr * 64 + m * 16 + ((l >> 4) << 2) + r) * 256 + wc * 64 + n * 16 + (l & 15)] =
            macc[m][n][r];
}

// =====================================================================
// 9) final gate + partial reduction over 16 ic-chunks
__global__ void k_final2(const float* __restrict__ part, const float* __restrict__ img,
                         const float* __restrict__ aud, const float* __restrict__ t_o,
                         float* __restrict__ out0, float* __restrict__ out1) {
  int i = blockIdx.x * 256 + threadIdx.x;
  float t = t_o[0];
  float4 m = {0.f, 0.f, 0.f, 0.f};
#pragma unroll
  for (int ic = 0; ic < 16; ic++) {
    float4 p = ((const float4*)(part + ic * 524288))[i];
    m.x += p.x; m.y += p.y; m.z += p.z; m.w += p.w;
  }
  float4 a = ((const float4*)img)[i];
  float4 u = ((const float4*)aud)[i];
  float4 o0, o1;
  {
    float j = 1.f / (1.f + __expf(-m.x)); float Z = t * j * a.x + (1.f - j) * u.x;
    o0.x = Z + a.x; o1.x = Z + u.x;
  }
  {
    float j = 1.f / (1.f + __expf(-m.y)); float Z = t * j * a.y + (1.f - j) * u.y;
    o0.y = Z + a.y; o1.y = Z + u.y;
  }
  {
    float j = 1.f / (1.f + __expf(-m.z)); float Z = t * j * a.z + (1.f - j) * u.z;
    o0.z = Z + a.z; o1.z = Z + u.z;
  }
  {
    float j = 1.f / (1.f + __expf(-m.w)); float Z = t * j * a.w + (1.f - j) * u.w;
    o0.w = Z + a.w; o1.w = Z + u.w;
  }
  ((float4*)out0)[i] = o0;
  ((float4*)out1)[i] = o1;
}

// =====================================================================
extern "C" void kernel_launch(void* const* d_in, const int* in_sizes, int n_in,
                              void* d_out, int out_size, void* d_ws, size_t ws_size,
                              hipStream_t stream) {
  const float* img   = (const float*)d_in[0];
  const float* aud   = (const float*)d_in[1];
  const float* com   = (const float*)d_in[2];
  const float* qv_w  = (const float*)d_in[3];
  const float* qv_b  = (const float*)d_in[4];
  const float* qa_w  = (const float*)d_in[5];
  const float* qa_b  = (const float*)d_in[6];
  const float* kv_w  = (const float*)d_in[7];
  const float* kv_b  = (const float*)d_in[8];
  const float* ka_w  = (const float*)d_in[9];
  const float* ka_b  = (const float*)d_in[10];
  const float* cc_w  = (const float*)d_in[11];
  const float* cc_b  = (const float*)d_in[12];
  const float* w5_w  = (const float*)d_in[13];
  const float* w5_b  = (const float*)d_in[14];
  const float* w6_w  = (const float*)d_in[15];
  const float* w6_b  = (const float*)d_in[16];
  const float* w7_w  = (const float*)d_in[17];
  const float* w7_b  = (const float*)d_in[18];
  const float* w8_w  = (const float*)d_in[19];
  const float* w8_b  = (const float*)d_in[20];
  const float* bil_w = (const float*)d_in[21];
  const float* t_o   = (const float*)d_in[22];
  float* out = (float*)d_out;

  char* ws = (char*)d_ws;
  ushortT* act16  = (ushortT*)(ws + OFF_ACT16);
  ushortT* actT16 = (ushortT*)(ws + OFF_ACTT16);
  ushortT* w16t   = (ushortT*)(ws + OFF_W16T);
  ushortT* proj16 = (ushortT*)(ws + OFF_PROJ16);
  ushortT* P16    = (ushortT*)(ws + OFF_P16);
  ushortT* vc16   = (ushortT*)(ws + OFF_VC16);
  ushortT* ac16   = (ushortT*)(ws + OFF_AC16);
  float*   pvv32  = (float*)(ws + OFF_PVV32);
  float*   pva32  = (float*)(ws + OFF_PVA32);
  float*   part   = (float*)(ws + OFF_PART);
  ushortT* bil16  = (ushortT*)(ws + OFF_BIL16);
  ushortT* cfv16  = (ushortT*)(ws + OFF_CFV16);
  ushortT* cfa16  = (ushortT*)(ws + OFF_CFA16);

  k_cvt_acts<<<384, 256, 0, stream>>>(img, aud, com, act16);
  k_cvt_bil<<<2048, 256, 0, stream>>>(bil_w, bil16);
  k_transpose<<<528, 256, 0, stream>>>(img, aud, com, qv_w, qa_w, kv_w, ka_w, cc_w,
                                       w5_w, w6_w, w7_w, w8_w, actT16, w16t);
  k_linear5<<<320, 512, 0, stream>>>(act16, w16t, qv_b, qa_b, kv_b, ka_b, cc_b, proj16);
  k_attn<<<256, 512, 0, stream>>>(proj16, P16);
  k_pv<<<256, 512, 0, stream>>>(P16, actT16, pvv32, pva32, vc16, ac16);
  k_lin4c<<<128, 512, 0, stream>>>(vc16, ac16, w16t, w5_b, w6_b, w7_b, w8_b,
                                   pvv32, pva32, cfv16, cfa16);
  k_bilinear5<<<256, 512, 0, stream>>>(cfa16, cfv16, bil16, part);
  k_final2<<<512, 256, 0, stream>>>(part, img, aud, t_o, out, out + 524288);
}